// Round 1
// baseline (15023.578 us; speedup 1.0000x reference)
//
#include <hip/hip_runtime.h>
#include <cmath>

#define BATCH 64
#define SEQ   512
#define EMBED 384
#define HEADS 7
#define HSZ   54
#define FFND  2304
#define NTOK  (BATCH*SEQ)
#define EPS   1e-5f
#define SCALE 0.13608276348795434f  // 54^-0.5

// ---------------- LayerNorm: one wave per row ----------------
__global__ __launch_bounds__(256) void ln_kernel(const float* __restrict__ x,
    const float* __restrict__ g, const float* __restrict__ b, float* __restrict__ out) {
  int wave = threadIdx.x >> 6, lane = threadIdx.x & 63;
  int row = (blockIdx.x << 2) + wave;
  const float* xr = x + (size_t)row * EMBED;
  float v[6]; float s = 0.f;
#pragma unroll
  for (int i = 0; i < 6; ++i) { v[i] = xr[lane + (i << 6)]; s += v[i]; }
#pragma unroll
  for (int off = 32; off; off >>= 1) s += __shfl_xor(s, off);
  float mu = s * (1.f / EMBED);
  float var = 0.f;
#pragma unroll
  for (int i = 0; i < 6; ++i) { float d = v[i] - mu; var += d * d; }
#pragma unroll
  for (int off = 32; off; off >>= 1) var += __shfl_xor(var, off);
  float rstd = rsqrtf(var * (1.f / EMBED) + EPS);
  float* orow = out + (size_t)row * EMBED;
#pragma unroll
  for (int i = 0; i < 6; ++i) {
    int c = lane + (i << 6);
    orow[c] = (v[i] - mu) * rstd * g[c] + b[c];
  }
}

// ---------------- QKV projection: 64tok x 54(+pad) per block, reg-tiled 4x4 ----------------
// grid: (NTOK/64, 21)  y: head = y%7, type = y/7 (0=q,1=k,2=v)
__global__ __launch_bounds__(256) void qkv_kernel(const float* __restrict__ h,
    const float* __restrict__ wq, const float* __restrict__ wk, const float* __restrict__ wv,
    const float* __restrict__ bq, const float* __restrict__ bk, const float* __restrict__ bv,
    float* __restrict__ qo, float* __restrict__ ko, float* __restrict__ vo) {
  __shared__ float hs[64 * 68];   // [tok][d]  stride 68 (17 float4) -> 2-way max conflict
  __shared__ float wsm[64 * 68];  // [j][d]    transposed weight
  int tid = threadIdx.x;
  int head = blockIdx.y % HEADS, type = blockIdx.y / HEADS;
  const float* W = (type == 0) ? wq : (type == 1) ? wk : wv;
  const float* B = (type == 0) ? bq : (type == 1) ? bk : bv;
  float* O = (type == 0) ? qo : (type == 1) ? ko : vo;
  W += (size_t)head * EMBED * HSZ;
  int tok0 = blockIdx.x << 6;
  int tx = tid & 15, ty = tid >> 4;
  float acc[4][4] = {};
  for (int d0 = 0; d0 < EMBED; d0 += 64) {
    for (int e = tid; e < 4096; e += 256) {
      int t = e >> 6, c = e & 63;
      hs[t * 68 + c] = h[(size_t)(tok0 + t) * EMBED + d0 + c];
    }
    for (int e = tid; e < 4096; e += 256) {
      int j = e >> 6, c = e & 63;   // LDS-write conflict-free; global L2-resident strided read
      wsm[j * 68 + c] = (j < HSZ) ? W[(size_t)(d0 + c) * HSZ + j] : 0.f;
    }
    __syncthreads();
#pragma unroll
    for (int d4 = 0; d4 < 16; ++d4) {
      float4 hv[4], wv4[4];
#pragma unroll
      for (int i = 0; i < 4; ++i) hv[i]  = *reinterpret_cast<const float4*>(&hs[(ty * 4 + i) * 68 + d4 * 4]);
#pragma unroll
      for (int i = 0; i < 4; ++i) wv4[i] = *reinterpret_cast<const float4*>(&wsm[(tx * 4 + i) * 68 + d4 * 4]);
#pragma unroll
      for (int a = 0; a < 4; ++a)
#pragma unroll
        for (int bj = 0; bj < 4; ++bj)
          acc[a][bj] += hv[a].x * wv4[bj].x + hv[a].y * wv4[bj].y +
                        hv[a].z * wv4[bj].z + hv[a].w * wv4[bj].w;
    }
    __syncthreads();
  }
#pragma unroll
  for (int a = 0; a < 4; ++a) {
    int token = tok0 + ty * 4 + a;
    int bb = token >> 9, ss = token & 511;
#pragma unroll
    for (int bj = 0; bj < 4; ++bj) {
      int j = tx * 4 + bj;
      if (j < HSZ)
        O[((size_t)(bb * HEADS + head) * SEQ + ss) * HSZ + j] = acc[a][bj] + B[head * HSZ + j];
    }
  }
}

// ---------------- Flash-style causal attention ----------------
// grid: (SEQ/64, BATCH*HEADS), block 256.  thread: row r = tid>>2 (64 rows), sub = tid&3.
__global__ __launch_bounds__(256) void attn_kernel(const float* __restrict__ q,
    const float* __restrict__ k, const float* __restrict__ v, float* __restrict__ o) {
  __shared__ float qs[64 * 60], ks[64 * 60], vs[64 * 60];  // stride 60 = 15 float4, 16B aligned
  __shared__ float ps[64 * 65];                            // stride 65: conflict-free row access
  int tid = threadIdx.x;
  int bh = blockIdx.y;
  int qt = blockIdx.x;
  int qr0 = qt << 6;
  const float* qbase = q + (size_t)bh * SEQ * HSZ;
  const float* kbase = k + (size_t)bh * SEQ * HSZ;
  const float* vbase = v + (size_t)bh * SEQ * HSZ;

  if (tid < 64) {  // zero pads (cols 54..59) — required: LDS may hold stale/NaN bits
#pragma unroll
    for (int c = HSZ; c < 60; ++c) { qs[tid * 60 + c] = 0.f; ks[tid * 60 + c] = 0.f; vs[tid * 60 + c] = 0.f; }
  }
  for (int e = tid; e < 64 * HSZ; e += 256) {
    int r = e / HSZ, c = e % HSZ;
    qs[r * 60 + c] = qbase[(size_t)qr0 * HSZ + e];   // contiguous
  }
  __syncthreads();
  int r = tid >> 2, sub = tid & 3;
  float4 qreg[14];
#pragma unroll
  for (int d4 = 0; d4 < 14; ++d4) qreg[d4] = *reinterpret_cast<const float4*>(&qs[r * 60 + d4 * 4]);

  float m = -1e30f, l = 0.f;
  float4 acc[4];
#pragma unroll
  for (int i = 0; i < 4; ++i) acc[i] = make_float4(0.f, 0.f, 0.f, 0.f);

  for (int kt = 0; kt <= qt; ++kt) {
    __syncthreads();  // previous tile fully consumed
    for (int e = tid; e < 64 * HSZ; e += 256) {
      int rr = e / HSZ, c = e % HSZ;
      ks[rr * 60 + c] = kbase[((size_t)kt << 6) * HSZ + e];
      vs[rr * 60 + c] = vbase[((size_t)kt << 6) * HSZ + e];
    }
    __syncthreads();
    float s[16];
    float mt = -1e30f;
#pragma unroll
    for (int i = 0; i < 16; ++i) {
      int c = i * 4 + sub;          // c = i*4+sub -> conflict-free ks banks across lanes
      float sv = 0.f;
#pragma unroll
      for (int d4 = 0; d4 < 14; ++d4) {
        float4 kv = *reinterpret_cast<const float4*>(&ks[c * 60 + d4 * 4]);
        sv += qreg[d4].x * kv.x + qreg[d4].y * kv.y + qreg[d4].z * kv.z + qreg[d4].w * kv.w;
      }
      sv *= SCALE;
      int col = (kt << 6) + c;
      if (col > qr0 + r) sv = -1e30f;   // causal
      s[i] = sv;
      mt = fmaxf(mt, sv);
    }
    mt = fmaxf(mt, __shfl_xor(mt, 1));
    mt = fmaxf(mt, __shfl_xor(mt, 2));
    float mnew = fmaxf(m, mt);
    float alpha = __expf(m - mnew);
    float lsum = 0.f;
#pragma unroll
    for (int i = 0; i < 16; ++i) {
      float p = __expf(s[i] - mnew);
      lsum += p;
      ps[r * 65 + i * 4 + sub] = p;
    }
    lsum += __shfl_xor(lsum, 1);
    lsum += __shfl_xor(lsum, 2);
    l = l * alpha + lsum;
    m = mnew;
#pragma unroll
    for (int j = 0; j < 4; ++j) { acc[j].x *= alpha; acc[j].y *= alpha; acc[j].z *= alpha; acc[j].w *= alpha; }
    // PV: row's ps written/read by the same 4 lanes (same wave) — no barrier needed
    for (int c = 0; c < 64; ++c) {
      float p = ps[r * 65 + c];
#pragma unroll
      for (int mm = 0; mm < 4; ++mm) {
        int d4 = sub + mm * 4;
        if (d4 < 15) {
          float4 vv = *reinterpret_cast<const float4*>(&vs[c * 60 + d4 * 4]);
          acc[mm].x += p * vv.x; acc[mm].y += p * vv.y; acc[mm].z += p * vv.z; acc[mm].w += p * vv.w;
        }
      }
    }
  }
  float linv = 1.f / l;
  float* obase = o + ((size_t)bh * SEQ + qr0 + r) * HSZ;
#pragma unroll
  for (int mm = 0; mm < 4; ++mm) {
    int d4 = sub + mm * 4;
    if (d4 < 14) {
      float vals[4] = {acc[mm].x, acc[mm].y, acc[mm].z, acc[mm].w};
#pragma unroll
      for (int e = 0; e < 4; ++e) {
        int d = d4 * 4 + e;
        if (d < HSZ) obase[d] = vals[e] * linv;
      }
    }
  }
}

// ---------------- O projection + residual: 64tok x 64j per block, 4x4 reg tile ----------------
// grid: (NTOK/64, EMBED/64)
__global__ __launch_bounds__(256) void oproj_kernel(const float* __restrict__ o,
    const float* __restrict__ x, const float* __restrict__ wo, const float* __restrict__ bo,
    float* __restrict__ x1) {
  __shared__ float os[64 * 60];   // [tok][d<54 +pad]
  __shared__ float wsm[64 * 60];  // [j][d] transposed
  int tid = threadIdx.x;
  int tok0 = blockIdx.x << 6;
  int j0 = blockIdx.y << 6;
  int tx = tid & 15, ty = tid >> 4;
  int bb = tok0 >> 9, s0 = tok0 & 511;
  float acc[4][4] = {};
  if (tid < 64) {
#pragma unroll
    for (int c = HSZ; c < 60; ++c) { os[tid * 60 + c] = 0.f; wsm[tid * 60 + c] = 0.f; }
  }
  for (int hh = 0; hh < HEADS; ++hh) {
    __syncthreads();
    const float* obase = o + ((size_t)(bb * HEADS + hh) * SEQ + s0) * HSZ;
    for (int e = tid; e < 64 * HSZ; e += 256) {
      int t = e / HSZ, c = e % HSZ;
      os[t * 60 + c] = obase[e];    // contiguous
    }
    for (int e = tid; e < 64 * HSZ; e += 256) {
      int c = e >> 6, j = e & 63;   // coalesced global; LDS write conflicts acceptable (staging)
      wsm[j * 60 + c] = wo[(size_t)(hh * HSZ + c) * EMBED + j0 + j];
    }
    __syncthreads();
#pragma unroll
    for (int d4 = 0; d4 < 14; ++d4) {
      float4 ov[4], wv4[4];
#pragma unroll
      for (int i = 0; i < 4; ++i) ov[i]  = *reinterpret_cast<const float4*>(&os[(ty * 4 + i) * 60 + d4 * 4]);
#pragma unroll
      for (int i = 0; i < 4; ++i) wv4[i] = *reinterpret_cast<const float4*>(&wsm[(tx * 4 + i) * 60 + d4 * 4]);
#pragma unroll
      for (int a = 0; a < 4; ++a)
#pragma unroll
        for (int bj = 0; bj < 4; ++bj)
          acc[a][bj] += ov[a].x * wv4[bj].x + ov[a].y * wv4[bj].y +
                        ov[a].z * wv4[bj].z + ov[a].w * wv4[bj].w;
    }
  }
#pragma unroll
  for (int a = 0; a < 4; ++a) {
    int token = tok0 + ty * 4 + a;
#pragma unroll
    for (int bj = 0; bj < 4; ++bj) {
      int j = j0 + tx * 4 + bj;
      size_t idx = (size_t)token * EMBED + j;
      x1[idx] = x[idx] + acc[a][bj] + bo[j];
    }
  }
}

// ---------------- Fused FFN: out = x1 + GELU(h2@w1+b1)@w2 + b2 ----------------
// block: 384 threads, 32 tokens; FFN dim processed in 48-wide chunks via LDS
__global__ __launch_bounds__(384) void ffn_kernel(const float* __restrict__ h2,
    const float* __restrict__ x1, const float* __restrict__ w1, const float* __restrict__ b1,
    const float* __restrict__ w2, const float* __restrict__ b2, float* __restrict__ out) {
  __shared__ float hs[32 * 388];  // stride 388 -> conflict-free broadcast reads
  __shared__ float gs[32 * 48];   // GELU chunk, stride 48 (16B aligned)
  int tid = threadIdx.x;
  int tok0 = blockIdx.x << 5;
  for (int e = tid; e < 32 * EMBED; e += 384) {
    int t = e / EMBED, d = e % EMBED;
    hs[t * 388 + d] = h2[(size_t)(tok0 + t) * EMBED + d];
  }
  __syncthreads();
  float acc2[32] = {};
  int tg = tid / 12, fg = tid % 12;
  for (int f0 = 0; f0 < FFND; f0 += 48) {
    float a1[4];
#pragma unroll
    for (int i = 0; i < 4; ++i) a1[i] = b1[f0 + fg * 4 + i];
    for (int d = 0; d < EMBED; ++d) {
      float hv = hs[tg * 388 + d];
      float4 w4 = *reinterpret_cast<const float4*>(&w1[(size_t)d * FFND + f0 + fg * 4]);
      a1[0] += hv * w4.x; a1[1] += hv * w4.y; a1[2] += hv * w4.z; a1[3] += hv * w4.w;
    }
#pragma unroll
    for (int i = 0; i < 4; ++i) {
      float xg = a1[i];
      gs[tg * 48 + fg * 4 + i] = 0.5f * xg * (1.f + erff(xg * 0.70710678118654752f));
    }
    __syncthreads();
    int j = tid;
#pragma unroll
    for (int f4 = 0; f4 < 12; ++f4) {
      float wa = w2[(size_t)(f0 + f4 * 4 + 0) * EMBED + j];
      float wb = w2[(size_t)(f0 + f4 * 4 + 1) * EMBED + j];
      float wc = w2[(size_t)(f0 + f4 * 4 + 2) * EMBED + j];
      float wd = w2[(size_t)(f0 + f4 * 4 + 3) * EMBED + j];
#pragma unroll
      for (int t = 0; t < 32; ++t) {
        float4 g4 = *reinterpret_cast<const float4*>(&gs[t * 48 + f4 * 4]);  // broadcast — free
        acc2[t] += g4.x * wa + g4.y * wb + g4.z * wc + g4.w * wd;
      }
    }
    __syncthreads();
  }
  int j = tid;
#pragma unroll
  for (int t = 0; t < 32; ++t) {
    size_t idx = (size_t)(tok0 + t) * EMBED + j;
    out[idx] = x1[idx] + acc2[t] + b2[j];
  }
}

extern "C" void kernel_launch(void* const* d_in, const int* in_sizes, int n_in,
                              void* d_out, int out_size, void* d_ws, size_t ws_size,
                              hipStream_t stream) {
  const float* x    = (const float*)d_in[0];
  const float* wq   = (const float*)d_in[1];
  const float* bq   = (const float*)d_in[2];
  const float* wk   = (const float*)d_in[3];
  const float* bk   = (const float*)d_in[4];
  const float* wv   = (const float*)d_in[5];
  const float* bv   = (const float*)d_in[6];
  const float* wo   = (const float*)d_in[7];
  const float* bo   = (const float*)d_in[8];
  const float* w1   = (const float*)d_in[9];
  const float* b1   = (const float*)d_in[10];
  const float* w2   = (const float*)d_in[11];
  const float* b2   = (const float*)d_in[12];
  const float* ln1g = (const float*)d_in[13];
  const float* ln1b = (const float*)d_in[14];
  const float* ln2g = (const float*)d_in[15];
  const float* ln2b = (const float*)d_in[16];
  float* out = (float*)d_out;

  // workspace layout (floats); x1 aliases q/k (dead after attention). Total ~249 MB.
  float* wsf  = (float*)d_ws;
  const size_t PERH = (size_t)BATCH * HEADS * SEQ * HSZ;  // 12,386,304
  float* hbuf = wsf;                                       // NTOK*EMBED
  float* qb   = hbuf + (size_t)NTOK * EMBED;
  float* kb   = qb + PERH;
  float* vb   = kb + PERH;
  float* ob   = vb + PERH;
  float* x1   = qb;  // alias

  ln_kernel  <<<NTOK / 4, 256, 0, stream>>>(x, ln1g, ln1b, hbuf);
  qkv_kernel <<<dim3(NTOK / 64, 21), 256, 0, stream>>>(hbuf, wq, wk, wv, bq, bk, bv, qb, kb, vb);
  attn_kernel<<<dim3(SEQ / 64, BATCH * HEADS), 256, 0, stream>>>(qb, kb, vb, ob);
  oproj_kernel<<<dim3(NTOK / 64, EMBED / 64), 256, 0, stream>>>(ob, x, wo, bo, x1);
  ln_kernel  <<<NTOK / 4, 256, 0, stream>>>(x1, ln2g, ln2b, hbuf);
  ffn_kernel <<<NTOK / 32, 384, 0, stream>>>(hbuf, x1, w1, b1, w2, b2, out);
}

// Round 2
// 3771.668 us; speedup vs baseline: 3.9833x; 3.9833x over previous
//
#include <hip/hip_runtime.h>
#include <hip/hip_bf16.h>
#include <cmath>

#define BATCH 64
#define SEQ   512
#define EMBED 384
#define HEADS 7
#define HSZ   54
#define FFND  2304
#define NTOK  (BATCH*SEQ)
#define EPS   1e-5f
#define SCALE 0.13608276348795434f  // 54^-0.5

typedef __attribute__((ext_vector_type(8))) short s16x8;
typedef __attribute__((ext_vector_type(4))) float f32x4;

__device__ __forceinline__ ushort f2bf(float f) {
  __hip_bfloat16 h = __float2bfloat16(f);
  return *reinterpret_cast<ushort*>(&h);
}

__device__ __forceinline__ void gload16(const void* g, void* l) {
  __builtin_amdgcn_global_load_lds((const __attribute__((address_space(1))) void*)g,
                                   (__attribute__((address_space(3))) void*)l, 16, 0, 0);
}

// ---------------- LayerNorm: one wave per row (fp32 out) ----------------
__global__ __launch_bounds__(256) void ln_kernel(const float* __restrict__ x,
    const float* __restrict__ g, const float* __restrict__ b, float* __restrict__ out) {
  int wave = threadIdx.x >> 6, lane = threadIdx.x & 63;
  int row = (blockIdx.x << 2) + wave;
  const float* xr = x + (size_t)row * EMBED;
  float v[6]; float s = 0.f;
#pragma unroll
  for (int i = 0; i < 6; ++i) { v[i] = xr[lane + (i << 6)]; s += v[i]; }
#pragma unroll
  for (int off = 32; off; off >>= 1) s += __shfl_xor(s, off);
  float mu = s * (1.f / EMBED);
  float var = 0.f;
#pragma unroll
  for (int i = 0; i < 6; ++i) { float d = v[i] - mu; var += d * d; }
#pragma unroll
  for (int off = 32; off; off >>= 1) var += __shfl_xor(var, off);
  float rstd = rsqrtf(var * (1.f / EMBED) + EPS);
  float* orow = out + (size_t)row * EMBED;
#pragma unroll
  for (int i = 0; i < 6; ++i) {
    int c = lane + (i << 6);
    orow[c] = (v[i] - mu) * rstd * g[c] + b[c];
  }
}

// ---------------- LayerNorm variant: bf16 out ----------------
__global__ __launch_bounds__(256) void ln_bf16_kernel(const float* __restrict__ x,
    const float* __restrict__ g, const float* __restrict__ b, ushort* __restrict__ out) {
  int wave = threadIdx.x >> 6, lane = threadIdx.x & 63;
  int row = (blockIdx.x << 2) + wave;
  const float* xr = x + (size_t)row * EMBED;
  float v[6]; float s = 0.f;
#pragma unroll
  for (int i = 0; i < 6; ++i) { v[i] = xr[lane + (i << 6)]; s += v[i]; }
#pragma unroll
  for (int off = 32; off; off >>= 1) s += __shfl_xor(s, off);
  float mu = s * (1.f / EMBED);
  float var = 0.f;
#pragma unroll
  for (int i = 0; i < 6; ++i) { float d = v[i] - mu; var += d * d; }
#pragma unroll
  for (int off = 32; off; off >>= 1) var += __shfl_xor(var, off);
  float rstd = rsqrtf(var * (1.f / EMBED) + EPS);
  ushort* orow = out + (size_t)row * EMBED;
#pragma unroll
  for (int i = 0; i < 6; ++i) {
    int c = lane + (i << 6);
    orow[c] = f2bf((v[i] - mu) * rstd * g[c] + b[c]);
  }
}

// ---------------- transpose+convert: out[n*K+k] = bf16(in[k*N+n]) ----------------
__global__ __launch_bounds__(256) void convT_kernel(const float* __restrict__ in,
    ushort* __restrict__ out, int K, int N) {
  int idx = blockIdx.x * 256 + threadIdx.x;
  if (idx >= N * K) return;
  int n = idx / K, k = idx - n * K;
  out[idx] = f2bf(in[(size_t)k * N + n]);
}

// ---------------- QKV projection (fp32, unchanged) ----------------
__global__ __launch_bounds__(256) void qkv_kernel(const float* __restrict__ h,
    const float* __restrict__ wq, const float* __restrict__ wk, const float* __restrict__ wv,
    const float* __restrict__ bq, const float* __restrict__ bk, const float* __restrict__ bv,
    float* __restrict__ qo, float* __restrict__ ko, float* __restrict__ vo) {
  __shared__ float hs[64 * 68];
  __shared__ float wsm[64 * 68];
  int tid = threadIdx.x;
  int head = blockIdx.y % HEADS, type = blockIdx.y / HEADS;
  const float* W = (type == 0) ? wq : (type == 1) ? wk : wv;
  const float* B = (type == 0) ? bq : (type == 1) ? bk : bv;
  float* O = (type == 0) ? qo : (type == 1) ? ko : vo;
  W += (size_t)head * EMBED * HSZ;
  int tok0 = blockIdx.x << 6;
  int tx = tid & 15, ty = tid >> 4;
  float acc[4][4] = {};
  for (int d0 = 0; d0 < EMBED; d0 += 64) {
    for (int e = tid; e < 4096; e += 256) {
      int t = e >> 6, c = e & 63;
      hs[t * 68 + c] = h[(size_t)(tok0 + t) * EMBED + d0 + c];
    }
    for (int e = tid; e < 4096; e += 256) {
      int j = e >> 6, c = e & 63;
      wsm[j * 68 + c] = (j < HSZ) ? W[(size_t)(d0 + c) * HSZ + j] : 0.f;
    }
    __syncthreads();
#pragma unroll
    for (int d4 = 0; d4 < 16; ++d4) {
      float4 hv[4], wv4[4];
#pragma unroll
      for (int i = 0; i < 4; ++i) hv[i]  = *reinterpret_cast<const float4*>(&hs[(ty * 4 + i) * 68 + d4 * 4]);
#pragma unroll
      for (int i = 0; i < 4; ++i) wv4[i] = *reinterpret_cast<const float4*>(&wsm[(tx * 4 + i) * 68 + d4 * 4]);
#pragma unroll
      for (int a = 0; a < 4; ++a)
#pragma unroll
        for (int bj = 0; bj < 4; ++bj)
          acc[a][bj] += hv[a].x * wv4[bj].x + hv[a].y * wv4[bj].y +
                        hv[a].z * wv4[bj].z + hv[a].w * wv4[bj].w;
    }
    __syncthreads();
  }
#pragma unroll
  for (int a = 0; a < 4; ++a) {
    int token = tok0 + ty * 4 + a;
    int bb = token >> 9, ss = token & 511;
#pragma unroll
    for (int bj = 0; bj < 4; ++bj) {
      int j = tx * 4 + bj;
      if (j < HSZ)
        O[((size_t)(bb * HEADS + head) * SEQ + ss) * HSZ + j] = acc[a][bj] + B[head * HSZ + j];
    }
  }
}

// ---------------- Flash-style causal attention (fp32, unchanged) ----------------
__global__ __launch_bounds__(256) void attn_kernel(const float* __restrict__ q,
    const float* __restrict__ k, const float* __restrict__ v, float* __restrict__ o) {
  __shared__ float qs[64 * 60], ks[64 * 60], vs[64 * 60];
  __shared__ float ps[64 * 65];
  int tid = threadIdx.x;
  int bh = blockIdx.y;
  int qt = blockIdx.x;
  int qr0 = qt << 6;
  const float* qbase = q + (size_t)bh * SEQ * HSZ;
  const float* kbase = k + (size_t)bh * SEQ * HSZ;
  const float* vbase = v + (size_t)bh * SEQ * HSZ;

  if (tid < 64) {
#pragma unroll
    for (int c = HSZ; c < 60; ++c) { qs[tid * 60 + c] = 0.f; ks[tid * 60 + c] = 0.f; vs[tid * 60 + c] = 0.f; }
  }
  for (int e = tid; e < 64 * HSZ; e += 256) {
    int r = e / HSZ, c = e % HSZ;
    qs[r * 60 + c] = qbase[(size_t)qr0 * HSZ + e];
  }
  __syncthreads();
  int r = tid >> 2, sub = tid & 3;
  float4 qreg[14];
#pragma unroll
  for (int d4 = 0; d4 < 14; ++d4) qreg[d4] = *reinterpret_cast<const float4*>(&qs[r * 60 + d4 * 4]);

  float m = -1e30f, l = 0.f;
  float4 acc[4];
#pragma unroll
  for (int i = 0; i < 4; ++i) acc[i] = make_float4(0.f, 0.f, 0.f, 0.f);

  for (int kt = 0; kt <= qt; ++kt) {
    __syncthreads();
    for (int e = tid; e < 64 * HSZ; e += 256) {
      int rr = e / HSZ, c = e % HSZ;
      ks[rr * 60 + c] = kbase[((size_t)kt << 6) * HSZ + e];
      vs[rr * 60 + c] = vbase[((size_t)kt << 6) * HSZ + e];
    }
    __syncthreads();
    float s[16];
    float mt = -1e30f;
#pragma unroll
    for (int i = 0; i < 16; ++i) {
      int c = i * 4 + sub;
      float sv = 0.f;
#pragma unroll
      for (int d4 = 0; d4 < 14; ++d4) {
        float4 kv = *reinterpret_cast<const float4*>(&ks[c * 60 + d4 * 4]);
        sv += qreg[d4].x * kv.x + qreg[d4].y * kv.y + qreg[d4].z * kv.z + qreg[d4].w * kv.w;
      }
      sv *= SCALE;
      int col = (kt << 6) + c;
      if (col > qr0 + r) sv = -1e30f;
      s[i] = sv;
      mt = fmaxf(mt, sv);
    }
    mt = fmaxf(mt, __shfl_xor(mt, 1));
    mt = fmaxf(mt, __shfl_xor(mt, 2));
    float mnew = fmaxf(m, mt);
    float alpha = __expf(m - mnew);
    float lsum = 0.f;
#pragma unroll
    for (int i = 0; i < 16; ++i) {
      float p = __expf(s[i] - mnew);
      lsum += p;
      ps[r * 65 + i * 4 + sub] = p;
    }
    lsum += __shfl_xor(lsum, 1);
    lsum += __shfl_xor(lsum, 2);
    l = l * alpha + lsum;
    m = mnew;
#pragma unroll
    for (int j = 0; j < 4; ++j) { acc[j].x *= alpha; acc[j].y *= alpha; acc[j].z *= alpha; acc[j].w *= alpha; }
    for (int c = 0; c < 64; ++c) {
      float p = ps[r * 65 + c];
#pragma unroll
      for (int mm = 0; mm < 4; ++mm) {
        int d4 = sub + mm * 4;
        if (d4 < 15) {
          float4 vv = *reinterpret_cast<const float4*>(&vs[c * 60 + d4 * 4]);
          acc[mm].x += p * vv.x; acc[mm].y += p * vv.y; acc[mm].z += p * vv.z; acc[mm].w += p * vv.w;
        }
      }
    }
  }
  float linv = 1.f / l;
  float* obase = o + ((size_t)bh * SEQ + qr0 + r) * HSZ;
#pragma unroll
  for (int mm = 0; mm < 4; ++mm) {
    int d4 = sub + mm * 4;
    if (d4 < 14) {
      float vals[4] = {acc[mm].x, acc[mm].y, acc[mm].z, acc[mm].w};
#pragma unroll
      for (int e = 0; e < 4; ++e) {
        int d = d4 * 4 + e;
        if (d < HSZ) obase[d] = vals[e] * linv;
      }
    }
  }
}

// ---------------- O projection + residual (fp32, unchanged) ----------------
__global__ __launch_bounds__(256) void oproj_kernel(const float* __restrict__ o,
    const float* __restrict__ x, const float* __restrict__ wo, const float* __restrict__ bo,
    float* __restrict__ x1) {
  __shared__ float os[64 * 60];
  __shared__ float wsm[64 * 60];
  int tid = threadIdx.x;
  int tok0 = blockIdx.x << 6;
  int j0 = blockIdx.y << 6;
  int tx = tid & 15, ty = tid >> 4;
  int bb = tok0 >> 9, s0 = tok0 & 511;
  float acc[4][4] = {};
  if (tid < 64) {
#pragma unroll
    for (int c = HSZ; c < 60; ++c) { os[tid * 60 + c] = 0.f; wsm[tid * 60 + c] = 0.f; }
  }
  for (int hh = 0; hh < HEADS; ++hh) {
    __syncthreads();
    const float* obase = o + ((size_t)(bb * HEADS + hh) * SEQ + s0) * HSZ;
    for (int e = tid; e < 64 * HSZ; e += 256) {
      int t = e / HSZ, c = e % HSZ;
      os[t * 60 + c] = obase[e];
    }
    for (int e = tid; e < 64 * HSZ; e += 256) {
      int c = e >> 6, j = e & 63;
      wsm[j * 60 + c] = wo[(size_t)(hh * HSZ + c) * EMBED + j0 + j];
    }
    __syncthreads();
#pragma unroll
    for (int d4 = 0; d4 < 14; ++d4) {
      float4 ov[4], wv4[4];
#pragma unroll
      for (int i = 0; i < 4; ++i) ov[i]  = *reinterpret_cast<const float4*>(&os[(ty * 4 + i) * 60 + d4 * 4]);
#pragma unroll
      for (int i = 0; i < 4; ++i) wv4[i] = *reinterpret_cast<const float4*>(&wsm[(tx * 4 + i) * 60 + d4 * 4]);
#pragma unroll
      for (int a = 0; a < 4; ++a)
#pragma unroll
        for (int bj = 0; bj < 4; ++bj)
          acc[a][bj] += ov[a].x * wv4[bj].x + ov[a].y * wv4[bj].y +
                        ov[a].z * wv4[bj].z + ov[a].w * wv4[bj].w;
    }
  }
#pragma unroll
  for (int a = 0; a < 4; ++a) {
    int token = tok0 + ty * 4 + a;
#pragma unroll
    for (int bj = 0; bj < 4; ++bj) {
      int j = j0 + tx * 4 + bj;
      size_t idx = (size_t)token * EMBED + j;
      x1[idx] = x[idx] + acc[a][bj] + bo[j];
    }
  }
}

// ---------------- bf16 MFMA GEMM (m97 structure: 128x128 tile, BK=64, 4 waves) ----------------
// A: [M][K] bf16 row-major (lda bytes). Bt: [N][K] bf16 row-major (ldb bytes).
// GELU=true : C = bf16( gelu(A@B + bias) ), ncols stride.
// GELU=false: C = fp32( A@B + bias + resid ), ncols stride.
template<int KSTEPS, int LDA, int LDB, bool GELU>
__global__ __launch_bounds__(256) void mfma_gemm(
    const char* __restrict__ Ab, const char* __restrict__ Btb,
    const float* __restrict__ bias, const float* __restrict__ resid,
    char* __restrict__ Cb, int ncols) {
  __shared__ ushort As[8192];  // [128 rows][64 k] bf16, XOR-swizzled columns
  __shared__ ushort Bs[8192];  // [128 n][64 k]
  int tid = threadIdx.x;
  int wv = tid >> 6, l = tid & 63;
  int wr = wv >> 1, wc = wv & 1;
  int lr = l & 15, lg = l >> 4;
  int tok0 = blockIdx.x << 7;
  int col0 = blockIdx.y << 7;

  // staging sources: lane chunk i covers LDS bytes [i*16, i*16+16) linearly;
  // pre-swizzle the GLOBAL column so that swizzled ds_reads see linear data (rule 21)
  const char* aptr[4]; const char* bptr[4];
#pragma unroll
  for (int is = 0; is < 4; ++is) {
    int i = is * 256 + tid;
    int row = i >> 3;
    int boff = (i & 7) << 4;
    int sw = boff ^ ((row & 7) << 4);
    aptr[is] = Ab + (size_t)(tok0 + row) * LDA + sw;
    bptr[is] = Btb + (size_t)(col0 + row) * LDB + sw;
  }

  // fragment read offsets (ushort elements), constant across K-steps
  int offA[2][4], offB[2][4];
#pragma unroll
  for (int m = 0; m < 4; ++m) {
    int rowa = wr * 64 + m * 16 + lr;
    int rowb = wc * 64 + m * 16 + lr;
    int sa = (rowa & 7) << 4, sb = (rowb & 7) << 4;
#pragma unroll
    for (int kk = 0; kk < 2; ++kk) {
      int kb = kk * 64 + lg * 16;
      offA[kk][m] = (rowa * 128 + (kb ^ sa)) >> 1;
      offB[kk][m] = (rowb * 128 + (kb ^ sb)) >> 1;
    }
  }

  f32x4 acc[4][4];
#pragma unroll
  for (int m = 0; m < 4; ++m)
#pragma unroll
    for (int n = 0; n < 4; ++n) acc[m][n] = (f32x4){0.f, 0.f, 0.f, 0.f};

  for (int ks = 0; ks < KSTEPS; ++ks) {
#pragma unroll
    for (int is = 0; is < 4; ++is) {
      gload16(aptr[is] + ks * 128, (char*)As + is * 4096 + wv * 1024);
      gload16(bptr[is] + ks * 128, (char*)Bs + is * 4096 + wv * 1024);
    }
    __syncthreads();  // drains vmcnt: staged tile visible
#pragma unroll
    for (int kk = 0; kk < 2; ++kk) {
      s16x8 af[4], bf[4];
#pragma unroll
      for (int m = 0; m < 4; ++m) af[m] = *reinterpret_cast<const s16x8*>(&As[offA[kk][m]]);
#pragma unroll
      for (int n = 0; n < 4; ++n) bf[n] = *reinterpret_cast<const s16x8*>(&Bs[offB[kk][n]]);
#pragma unroll
      for (int m = 0; m < 4; ++m)
#pragma unroll
        for (int n = 0; n < 4; ++n)
          acc[m][n] = __builtin_amdgcn_mfma_f32_16x16x32_bf16(af[m], bf[n], acc[m][n], 0, 0, 0);
    }
    __syncthreads();  // tile fully consumed before next stage
  }

  // epilogue. D frag: row = lg*4 + r (M/token dim), col = lr (N dim)  [m89-verified]
  int tokr = tok0 + wr * 64 + lg * 4;
  int colr = col0 + wc * 64 + lr;
  float bn[4];
#pragma unroll
  for (int n = 0; n < 4; ++n) bn[n] = bias[colr + n * 16];
  if constexpr (GELU) {
    ushort* C = (ushort*)Cb;
#pragma unroll
    for (int m = 0; m < 4; ++m)
#pragma unroll
      for (int r = 0; r < 4; ++r) {
        size_t rowbase = (size_t)(tokr + m * 16 + r) * ncols;
#pragma unroll
        for (int n = 0; n < 4; ++n) {
          float xg = acc[m][n][r] + bn[n];
          float ge = 0.5f * xg * (1.f + erff(xg * 0.70710678118654752f));
          C[rowbase + colr + n * 16] = f2bf(ge);
        }
      }
  } else {
    float* C = (float*)Cb;
#pragma unroll
    for (int m = 0; m < 4; ++m)
#pragma unroll
      for (int r = 0; r < 4; ++r) {
        size_t rowbase = (size_t)(tokr + m * 16 + r) * ncols;
#pragma unroll
        for (int n = 0; n < 4; ++n) {
          size_t idx = rowbase + colr + n * 16;
          C[idx] = acc[m][n][r] + bn[n] + resid[idx];
        }
      }
  }
}

extern "C" void kernel_launch(void* const* d_in, const int* in_sizes, int n_in,
                              void* d_out, int out_size, void* d_ws, size_t ws_size,
                              hipStream_t stream) {
  const float* x    = (const float*)d_in[0];
  const float* wq   = (const float*)d_in[1];
  const float* bq   = (const float*)d_in[2];
  const float* wk   = (const float*)d_in[3];
  const float* bk   = (const float*)d_in[4];
  const float* wv   = (const float*)d_in[5];
  const float* bv   = (const float*)d_in[6];
  const float* wo   = (const float*)d_in[7];
  const float* bo   = (const float*)d_in[8];
  const float* w1   = (const float*)d_in[9];
  const float* b1   = (const float*)d_in[10];
  const float* w2   = (const float*)d_in[11];
  const float* b2   = (const float*)d_in[12];
  const float* ln1g = (const float*)d_in[13];
  const float* ln1b = (const float*)d_in[14];
  const float* ln2g = (const float*)d_in[15];
  const float* ln2b = (const float*)d_in[16];
  float* out = (float*)d_out;

  // workspace byte layout (max footprint 248.5 MB, proven safe in round 1):
  //   [0, 50.33M)        hbuf fp32 (ln1 out)  -> REUSED as x1 fp32 (oproj out)
  //   [50.33M, 99.88M)   qb   -> later ffnb bf16 [NTOK][2304] spans [50.33M, 201.33M)
  //   [99.88M, 149.42M)  kb
  //   [149.42M,198.97M)  vb
  //   [198.97M,248.51M)  ob   -> later h2b bf16 [201.33M,226.49M), w1t, w2t
  char* wsb = (char*)d_ws;
  const size_t SZ_X  = (size_t)NTOK * EMBED * 4;          // 50,331,648
  const size_t SZ_PH = (size_t)BATCH * HEADS * SEQ * HSZ * 4;  // 49,545,216
  float*  hbuf = (float*)wsb;                  // also x1
  float*  x1   = (float*)wsb;
  float*  qb   = (float*)(wsb + SZ_X);
  float*  kb   = (float*)(wsb + SZ_X + SZ_PH);
  float*  vb   = (float*)(wsb + SZ_X + 2 * SZ_PH);
  float*  ob   = (float*)(wsb + SZ_X + 3 * SZ_PH);
  ushort* ffnb = (ushort*)(wsb + SZ_X);                        // 151.0 MB
  ushort* h2b  = (ushort*)(wsb + SZ_X + (size_t)NTOK * FFND * 2);  // 25.2 MB
  ushort* w1t  = (ushort*)((char*)h2b + (size_t)NTOK * EMBED * 2);
  ushort* w2t  = (ushort*)((char*)w1t + (size_t)EMBED * FFND * 2);

  ln_kernel  <<<NTOK / 4, 256, 0, stream>>>(x, ln1g, ln1b, hbuf);
  qkv_kernel <<<dim3(NTOK / 64, 21), 256, 0, stream>>>(hbuf, wq, wk, wv, bq, bk, bv, qb, kb, vb);
  attn_kernel<<<dim3(SEQ / 64, BATCH * HEADS), 256, 0, stream>>>(qb, kb, vb, ob);
  oproj_kernel<<<dim3(NTOK / 64, EMBED / 64), 256, 0, stream>>>(ob, x, wo, bo, x1);
  // weight conversions AFTER oproj: their region overlaps ob (dead from here on)
  convT_kernel<<<(EMBED * FFND + 255) / 256, 256, 0, stream>>>(w1, w1t, EMBED, FFND);  // w1t[j][d]
  convT_kernel<<<(EMBED * FFND + 255) / 256, 256, 0, stream>>>(w2, w2t, FFND, EMBED);  // w2t[d][f]
  ln_bf16_kernel<<<NTOK / 4, 256, 0, stream>>>(x1, ln2g, ln2b, h2b);
  // GEMM1: [NTOK,384]@[384,2304] + b1 -> gelu -> ffnb (bf16)
  mfma_gemm<EMBED / 64, EMBED * 2, EMBED * 2, true>
      <<<dim3(NTOK / 128, FFND / 128), 256, 0, stream>>>(
      (const char*)h2b, (const char*)w1t, b1, nullptr, (char*)ffnb, FFND);
  // GEMM2: [NTOK,2304]@[2304,384] + b2 + x1 -> out (fp32)
  mfma_gemm<FFND / 64, FFND * 2, FFND * 2, false>
      <<<dim3(NTOK / 128, EMBED / 128), 256, 0, stream>>>(
      (const char*)ffnb, (const char*)w2t, b2, x1, (char*)out, EMBED);
}

// Round 3
// 1127.677 us; speedup vs baseline: 13.3226x; 3.3446x over previous
//
#include <hip/hip_runtime.h>
#include <hip/hip_bf16.h>
#include <cmath>

#define BATCH 64
#define SEQ   512
#define EMBED 384
#define HEADS 7
#define HSZ   54
#define FFND  2304
#define NTOK  (BATCH*SEQ)
#define QKVN  1152   // 3*378 padded to 9*128
#define EPS   1e-5f
#define SCALE 0.13608276348795434f  // 54^-0.5

typedef __attribute__((ext_vector_type(8))) short s16x8;
typedef __attribute__((ext_vector_type(4))) float f32x4;

__device__ __forceinline__ ushort f2bf(float f) {
  __hip_bfloat16 h = __float2bfloat16(f);
  return *reinterpret_cast<ushort*>(&h);
}

__device__ __forceinline__ void gload16(const void* g, void* l) {
  __builtin_amdgcn_global_load_lds((const __attribute__((address_space(1))) void*)g,
                                   (__attribute__((address_space(3))) void*)l, 16, 0, 0);
}

// ---------------- LayerNorm -> bf16 out, one wave per row ----------------
__global__ __launch_bounds__(256) void ln_bf16_kernel(const float* __restrict__ x,
    const float* __restrict__ g, const float* __restrict__ b, ushort* __restrict__ out) {
  int wave = threadIdx.x >> 6, lane = threadIdx.x & 63;
  int row = (blockIdx.x << 2) + wave;
  const float* xr = x + (size_t)row * EMBED;
  float v[6]; float s = 0.f;
#pragma unroll
  for (int i = 0; i < 6; ++i) { v[i] = xr[lane + (i << 6)]; s += v[i]; }
#pragma unroll
  for (int off = 32; off; off >>= 1) s += __shfl_xor(s, off);
  float mu = s * (1.f / EMBED);
  float var = 0.f;
#pragma unroll
  for (int i = 0; i < 6; ++i) { float d = v[i] - mu; var += d * d; }
#pragma unroll
  for (int off = 32; off; off >>= 1) var += __shfl_xor(var, off);
  float rstd = rsqrtf(var * (1.f / EMBED) + EPS);
  ushort* orow = out + (size_t)row * EMBED;
#pragma unroll
  for (int i = 0; i < 6; ++i) {
    int c = lane + (i << 6);
    orow[c] = f2bf((v[i] - mu) * rstd * g[c] + b[c]);
  }
}

// ---------------- weight prep kernels ----------------
// wqkvt[n][k] bf16, n = type*378 + h*54 + hs (pad n>=1134 -> 0); bqkv[n] f32
__global__ __launch_bounds__(256) void conv_qkvw(const float* __restrict__ wq,
    const float* __restrict__ wk, const float* __restrict__ wv,
    const float* __restrict__ bq, const float* __restrict__ bk, const float* __restrict__ bv,
    ushort* __restrict__ wt, float* __restrict__ bqkv) {
  int idx = blockIdx.x * 256 + threadIdx.x;
  if (idx >= QKVN * EMBED) return;
  int n = idx / EMBED, k = idx - n * EMBED;
  float val = 0.f;
  if (n < 1134) {
    int type = n / 378, rem = n - type * 378;
    int h = rem / HSZ, hs = rem - h * HSZ;
    const float* W = (type == 0) ? wq : (type == 1) ? wk : wv;
    val = W[((size_t)h * EMBED + k) * HSZ + hs];
  }
  wt[idx] = f2bf(val);
  if (idx < QKVN) {
    float bval = 0.f;
    if (idx < 1134) {
      int type = idx / 378, rem = idx - type * 378;
      int h = rem / HSZ, hs = rem - h * HSZ;
      const float* B = (type == 0) ? bq : (type == 1) ? bk : bv;
      bval = B[h * HSZ + hs];
    }
    bqkv[idx] = bval;
  }
}

// wot[n][k] bf16 = wo[k][n] for k<378 else 0   (n,k in [0,384))
__global__ __launch_bounds__(256) void conv_wot(const float* __restrict__ wo,
    ushort* __restrict__ wt) {
  int idx = blockIdx.x * 256 + threadIdx.x;
  if (idx >= EMBED * EMBED) return;
  int n = idx / EMBED, k = idx - n * EMBED;
  wt[idx] = f2bf((k < 378) ? wo[(size_t)k * EMBED + n] : 0.f);
}

// out[n*K+k] = bf16(in[k*N+n])
__global__ __launch_bounds__(256) void convT_kernel(const float* __restrict__ in,
    ushort* __restrict__ out, int K, int N) {
  int idx = blockIdx.x * 256 + threadIdx.x;
  if (idx >= N * K) return;
  int n = idx / K, k = idx - n * K;
  out[idx] = f2bf(in[(size_t)k * N + n]);
}

// zero cols 378..383 of aout [NTOK][384]
__global__ __launch_bounds__(256) void pad_aout_kernel(ushort* __restrict__ aout) {
  int idx = blockIdx.x * 256 + threadIdx.x;
  if (idx >= NTOK * 6) return;
  int row = idx / 6, c = idx - row * 6;
  aout[(size_t)row * EMBED + 378 + c] = 0;
}

// ---------------- Flash-style causal attention (fp32 compute, bf16 io) ----------------
// qkv: [NTOK][1152] bf16, q at col h*54, k at 378+h*54, v at 756+h*54
// o:   [NTOK][384] bf16, col h*54
__global__ __launch_bounds__(256) void attn_kernel(const ushort* __restrict__ qkv,
    ushort* __restrict__ o) {
  __shared__ float qs[64 * 60], ks[64 * 60], vs[64 * 60];
  __shared__ float ps[64 * 65];
  int tid = threadIdx.x;
  int bh = blockIdx.y;
  int b = bh / HEADS, h = bh - b * HEADS;
  int qt = blockIdx.x;
  int qr0 = qt << 6;
  const ushort* base = qkv + (size_t)b * SEQ * QKVN + h * HSZ;

  if (tid < 64) {
#pragma unroll
    for (int c = HSZ; c < 60; ++c) { qs[tid * 60 + c] = 0.f; ks[tid * 60 + c] = 0.f; vs[tid * 60 + c] = 0.f; }
  }
  for (int e = tid; e < 64 * 27; e += 256) {
    int r = e / 27, c2 = e - r * 27;
    uint u = *reinterpret_cast<const uint*>(base + (size_t)(qr0 + r) * QKVN + c2 * 2);
    qs[r * 60 + c2 * 2]     = __uint_as_float(u << 16);
    qs[r * 60 + c2 * 2 + 1] = __uint_as_float(u & 0xffff0000u);
  }
  __syncthreads();
  int r = tid >> 2, sub = tid & 3;
  float4 qreg[14];
#pragma unroll
  for (int d4 = 0; d4 < 14; ++d4) qreg[d4] = *reinterpret_cast<const float4*>(&qs[r * 60 + d4 * 4]);

  float m = -1e30f, l = 0.f;
  float4 acc[4];
#pragma unroll
  for (int i = 0; i < 4; ++i) acc[i] = make_float4(0.f, 0.f, 0.f, 0.f);

  for (int kt = 0; kt <= qt; ++kt) {
    __syncthreads();
    for (int e = tid; e < 64 * 27; e += 256) {
      int rr = e / 27, c2 = e - rr * 27;
      size_t rowoff = (size_t)((kt << 6) + rr) * QKVN + c2 * 2;
      uint uk = *reinterpret_cast<const uint*>(base + 378 + rowoff);
      uint uv = *reinterpret_cast<const uint*>(base + 756 + rowoff);
      ks[rr * 60 + c2 * 2]     = __uint_as_float(uk << 16);
      ks[rr * 60 + c2 * 2 + 1] = __uint_as_float(uk & 0xffff0000u);
      vs[rr * 60 + c2 * 2]     = __uint_as_float(uv << 16);
      vs[rr * 60 + c2 * 2 + 1] = __uint_as_float(uv & 0xffff0000u);
    }
    __syncthreads();
    float s[16];
    float mt = -1e30f;
#pragma unroll
    for (int i = 0; i < 16; ++i) {
      int c = i * 4 + sub;
      float sv = 0.f;
#pragma unroll
      for (int d4 = 0; d4 < 14; ++d4) {
        float4 kv = *reinterpret_cast<const float4*>(&ks[c * 60 + d4 * 4]);
        sv += qreg[d4].x * kv.x + qreg[d4].y * kv.y + qreg[d4].z * kv.z + qreg[d4].w * kv.w;
      }
      sv *= SCALE;
      int col = (kt << 6) + c;
      if (col > qr0 + r) sv = -1e30f;
      s[i] = sv;
      mt = fmaxf(mt, sv);
    }
    mt = fmaxf(mt, __shfl_xor(mt, 1));
    mt = fmaxf(mt, __shfl_xor(mt, 2));
    float mnew = fmaxf(m, mt);
    float alpha = __expf(m - mnew);
    float lsum = 0.f;
#pragma unroll
    for (int i = 0; i < 16; ++i) {
      float p = __expf(s[i] - mnew);
      lsum += p;
      ps[r * 65 + i * 4 + sub] = p;
    }
    lsum += __shfl_xor(lsum, 1);
    lsum += __shfl_xor(lsum, 2);
    l = l * alpha + lsum;
    m = mnew;
#pragma unroll
    for (int j = 0; j < 4; ++j) { acc[j].x *= alpha; acc[j].y *= alpha; acc[j].z *= alpha; acc[j].w *= alpha; }
    for (int c = 0; c < 64; ++c) {
      float p = ps[r * 65 + c];
#pragma unroll
      for (int mm = 0; mm < 4; ++mm) {
        int d4 = sub + mm * 4;
        if (d4 < 15) {
          float4 vv = *reinterpret_cast<const float4*>(&vs[c * 60 + d4 * 4]);
          acc[mm].x += p * vv.x; acc[mm].y += p * vv.y; acc[mm].z += p * vv.z; acc[mm].w += p * vv.w;
        }
      }
    }
  }
  float linv = 1.f / l;
  ushort* obase = o + (size_t)(b * SEQ + qr0 + r) * EMBED + h * HSZ;
#pragma unroll
  for (int mm = 0; mm < 4; ++mm) {
    int d4 = sub + mm * 4;
    if (d4 < 14) {
      float vals[4] = {acc[mm].x, acc[mm].y, acc[mm].z, acc[mm].w};
#pragma unroll
      for (int e = 0; e < 4; ++e) {
        int d = d4 * 4 + e;
        if (d < HSZ) obase[d] = f2bf(vals[e] * linv);
      }
    }
  }
}

// ---------------- bf16 MFMA GEMM (m97 structure: 128x128 tile, BK=64, 4 waves) ----------------
// A: [M][K] bf16 (LDA bytes/row). Bt: [N][K] bf16 (LDB bytes/row).
// MODE 0: C = bf16(A@B + bias)            MODE 1: C = bf16(gelu(A@B + bias))
// MODE 2: C = f32 (A@B + bias + resid)
template<int KSTEPS, int LDA, int LDB, int MODE>
__global__ __launch_bounds__(256) void mfma_gemm(
    const char* __restrict__ Ab, const char* __restrict__ Btb,
    const float* __restrict__ bias, const float* __restrict__ resid,
    char* __restrict__ Cb, int ncols) {
  __shared__ ushort As[8192];  // [128 rows][64 k], XOR-swizzled
  __shared__ ushort Bs[8192];
  int tid = threadIdx.x;
  int wv = tid >> 6, l = tid & 63;
  int wr = wv >> 1, wc = wv & 1;
  int lr = l & 15, lg = l >> 4;
  int tok0 = blockIdx.x << 7;
  int col0 = blockIdx.y << 7;

  const char* aptr[4]; const char* bptr[4];
#pragma unroll
  for (int is = 0; is < 4; ++is) {
    int i = is * 256 + tid;
    int row = i >> 3;
    int boff = (i & 7) << 4;
    int sw = boff ^ ((row & 7) << 4);
    aptr[is] = Ab + (size_t)(tok0 + row) * LDA + sw;
    bptr[is] = Btb + (size_t)(col0 + row) * LDB + sw;
  }

  int offA[2][4], offB[2][4];
#pragma unroll
  for (int m = 0; m < 4; ++m) {
    int rowa = wr * 64 + m * 16 + lr;
    int rowb = wc * 64 + m * 16 + lr;
    int sa = (rowa & 7) << 4, sb = (rowb & 7) << 4;
#pragma unroll
    for (int kk = 0; kk < 2; ++kk) {
      int kb = kk * 64 + lg * 16;
      offA[kk][m] = (rowa * 128 + (kb ^ sa)) >> 1;
      offB[kk][m] = (rowb * 128 + (kb ^ sb)) >> 1;
    }
  }

  f32x4 acc[4][4];
#pragma unroll
  for (int m = 0; m < 4; ++m)
#pragma unroll
    for (int n = 0; n < 4; ++n) acc[m][n] = (f32x4){0.f, 0.f, 0.f, 0.f};

  for (int ks = 0; ks < KSTEPS; ++ks) {
#pragma unroll
    for (int is = 0; is < 4; ++is) {
      gload16(aptr[is] + ks * 128, (char*)As + is * 4096 + wv * 1024);
      gload16(bptr[is] + ks * 128, (char*)Bs + is * 4096 + wv * 1024);
    }
    __syncthreads();
#pragma unroll
    for (int kk = 0; kk < 2; ++kk) {
      s16x8 af[4], bfr[4];
#pragma unroll
      for (int m = 0; m < 4; ++m) af[m] = *reinterpret_cast<const s16x8*>(&As[offA[kk][m]]);
#pragma unroll
      for (int n = 0; n < 4; ++n) bfr[n] = *reinterpret_cast<const s16x8*>(&Bs[offB[kk][n]]);
#pragma unroll
      for (int m = 0; m < 4; ++m)
#pragma unroll
        for (int n = 0; n < 4; ++n)
          acc[m][n] = __builtin_amdgcn_mfma_f32_16x16x32_bf16(af[m], bfr[n], acc[m][n], 0, 0, 0);
    }
    __syncthreads();
  }

  int tokr = tok0 + wr * 64 + lg * 4;
  int colr = col0 + wc * 64 + lr;
  float bn[4];
#pragma unroll
  for (int n = 0; n < 4; ++n) bn[n] = bias[colr + n * 16];
  if constexpr (MODE == 2) {
    float* C = (float*)Cb;
#pragma unroll
    for (int m = 0; m < 4; ++m)
#pragma unroll
      for (int r = 0; r < 4; ++r) {
        size_t rowbase = (size_t)(tokr + m * 16 + r) * ncols;
#pragma unroll
        for (int n = 0; n < 4; ++n) {
          size_t idx = rowbase + colr + n * 16;
          C[idx] = acc[m][n][r] + bn[n] + resid[idx];
        }
      }
  } else {
    ushort* C = (ushort*)Cb;
#pragma unroll
    for (int m = 0; m < 4; ++m)
#pragma unroll
      for (int r = 0; r < 4; ++r) {
        size_t rowbase = (size_t)(tokr + m * 16 + r) * ncols;
#pragma unroll
        for (int n = 0; n < 4; ++n) {
          float xg = acc[m][n][r] + bn[n];
          if constexpr (MODE == 1)
            xg = 0.5f * xg * (1.f + erff(xg * 0.70710678118654752f));
          C[rowbase + colr + n * 16] = f2bf(xg);
        }
      }
  }
}

extern "C" void kernel_launch(void* const* d_in, const int* in_sizes, int n_in,
                              void* d_out, int out_size, void* d_ws, size_t ws_size,
                              hipStream_t stream) {
  const float* x    = (const float*)d_in[0];
  const float* wq   = (const float*)d_in[1];
  const float* bq   = (const float*)d_in[2];
  const float* wk   = (const float*)d_in[3];
  const float* bk   = (const float*)d_in[4];
  const float* wv   = (const float*)d_in[5];
  const float* bv   = (const float*)d_in[6];
  const float* wo   = (const float*)d_in[7];
  const float* bo   = (const float*)d_in[8];
  const float* w1   = (const float*)d_in[9];
  const float* b1   = (const float*)d_in[10];
  const float* w2   = (const float*)d_in[11];
  const float* b2   = (const float*)d_in[12];
  const float* ln1g = (const float*)d_in[13];
  const float* ln1b = (const float*)d_in[14];
  const float* ln2g = (const float*)d_in[15];
  const float* ln2b = (const float*)d_in[16];
  float* out = (float*)d_out;

  // workspace layout (bytes), total ~231 MB:
  //   [0, 50.33M)        x1 f32
  //   [50.33M, 201.33M)  ffnb bf16 [NTOK][2304]  (live only for GEMM1->GEMM2)
  //     overlaps: hb bf16 [50.33M,75.50M) (dead after qkv GEMM)
  //               qkvb bf16 [75.50M,150.99M) (dead after attn)
  //               aout bf16 [150.99M,176.16M) (dead after oproj)
  //   [201.33M, 226.49M) h2b bf16
  //   [226.49M, ...)     w1t, w2t, wqkvt, wot, bqkv
  char* wsb = (char*)d_ws;
  float*  x1    = (float*)wsb;
  ushort* ffnb  = (ushort*)(wsb + 50331648);
  ushort* hb    = (ushort*)(wsb + 50331648);
  ushort* qkvb  = (ushort*)(wsb + 75497472);
  ushort* aout  = (ushort*)(wsb + 150994944);
  ushort* h2b   = (ushort*)(wsb + 201326592);
  ushort* w1t   = (ushort*)(wsb + 226492416);
  ushort* w2t   = (ushort*)(wsb + 228261888);
  ushort* wqkvt = (ushort*)(wsb + 230031360);
  ushort* wot   = (ushort*)(wsb + 230916096);
  float*  bqkv  = (float*)(wsb + 231211008);

  // weight prep (region disjoint from all activations)
  conv_qkvw  <<<(QKVN * EMBED + 255) / 256, 256, 0, stream>>>(wq, wk, wv, bq, bk, bv, wqkvt, bqkv);
  conv_wot   <<<(EMBED * EMBED + 255) / 256, 256, 0, stream>>>(wo, wot);
  convT_kernel<<<(EMBED * FFND + 255) / 256, 256, 0, stream>>>(w1, w1t, EMBED, FFND);
  convT_kernel<<<(EMBED * FFND + 255) / 256, 256, 0, stream>>>(w2, w2t, FFND, EMBED);
  pad_aout_kernel<<<(NTOK * 6 + 255) / 256, 256, 0, stream>>>(aout);

  ln_bf16_kernel<<<NTOK / 4, 256, 0, stream>>>(x, ln1g, ln1b, hb);
  // QKV: [NTOK,384]@[384,1152] + bqkv -> qkvb bf16
  mfma_gemm<EMBED / 64, EMBED * 2, EMBED * 2, 0>
      <<<dim3(NTOK / 128, QKVN / 128), 256, 0, stream>>>(
      (const char*)hb, (const char*)wqkvt, bqkv, nullptr, (char*)qkvb, QKVN);
  attn_kernel<<<dim3(SEQ / 64, BATCH * HEADS), 256, 0, stream>>>(qkvb, aout);
  // O-proj: [NTOK,384]@[384,384] + bo + x -> x1 f32   (K cols 378..383 are zero)
  mfma_gemm<EMBED / 64, EMBED * 2, EMBED * 2, 2>
      <<<dim3(NTOK / 128, EMBED / 128), 256, 0, stream>>>(
      (const char*)aout, (const char*)wot, bo, x, (char*)x1, EMBED);
  ln_bf16_kernel<<<NTOK / 4, 256, 0, stream>>>(x1, ln2g, ln2b, h2b);
  // FFN GEMM1: [NTOK,384]@[384,2304] + b1 -> gelu -> ffnb bf16
  mfma_gemm<EMBED / 64, EMBED * 2, EMBED * 2, 1>
      <<<dim3(NTOK / 128, FFND / 128), 256, 0, stream>>>(
      (const char*)h2b, (const char*)w1t, b1, nullptr, (char*)ffnb, FFND);
  // FFN GEMM2: [NTOK,2304]@[2304,384] + b2 + x1 -> out f32
  mfma_gemm<FFND / 64, FFND * 2, FFND * 2, 2>
      <<<dim3(NTOK / 128, EMBED / 128), 256, 0, stream>>>(
      (const char*)ffnb, (const char*)w2t, b2, x1, (char*)out, EMBED);
}

// Round 4
// 526.910 us; speedup vs baseline: 28.5126x; 2.1402x over previous
//
#include <hip/hip_runtime.h>
#include <hip/hip_bf16.h>
#include <cmath>

#define BATCH 64
#define SEQ   512
#define EMBED 384
#define HEADS 7
#define HSZ   54
#define FFND  2304
#define NTOK  (BATCH*SEQ)
#define QKVN  1152   // 3*378 padded to 9*128
#define EPS   1e-5f
#define SCALE 0.13608276348795434f  // 54^-0.5
#define AST   72     // attention LDS row stride (ushorts); 144B = 9*16 -> b128-aligned

typedef __attribute__((ext_vector_type(8))) short s16x8;
typedef __attribute__((ext_vector_type(4))) float f32x4;

__device__ __forceinline__ ushort f2bf(float f) {
  __hip_bfloat16 h = __float2bfloat16(f);
  return *reinterpret_cast<ushort*>(&h);
}

__device__ __forceinline__ void gload16(const void* g, void* l) {
  __builtin_amdgcn_global_load_lds((const __attribute__((address_space(1))) void*)g,
                                   (__attribute__((address_space(3))) void*)l, 16, 0, 0);
}

// ---------------- LayerNorm -> bf16 out, one wave per row ----------------
__global__ __launch_bounds__(256) void ln_bf16_kernel(const float* __restrict__ x,
    const float* __restrict__ g, const float* __restrict__ b, ushort* __restrict__ out) {
  int wave = threadIdx.x >> 6, lane = threadIdx.x & 63;
  int row = (blockIdx.x << 2) + wave;
  const float* xr = x + (size_t)row * EMBED;
  float v[6]; float s = 0.f;
#pragma unroll
  for (int i = 0; i < 6; ++i) { v[i] = xr[lane + (i << 6)]; s += v[i]; }
#pragma unroll
  for (int off = 32; off; off >>= 1) s += __shfl_xor(s, off);
  float mu = s * (1.f / EMBED);
  float var = 0.f;
#pragma unroll
  for (int i = 0; i < 6; ++i) { float d = v[i] - mu; var += d * d; }
#pragma unroll
  for (int off = 32; off; off >>= 1) var += __shfl_xor(var, off);
  float rstd = rsqrtf(var * (1.f / EMBED) + EPS);
  ushort* orow = out + (size_t)row * EMBED;
#pragma unroll
  for (int i = 0; i < 6; ++i) {
    int c = lane + (i << 6);
    orow[c] = f2bf((v[i] - mu) * rstd * g[c] + b[c]);
  }
}

// ---------------- weight prep kernels ----------------
__global__ __launch_bounds__(256) void conv_qkvw(const float* __restrict__ wq,
    const float* __restrict__ wk, const float* __restrict__ wv,
    const float* __restrict__ bq, const float* __restrict__ bk, const float* __restrict__ bv,
    ushort* __restrict__ wt, float* __restrict__ bqkv) {
  int idx = blockIdx.x * 256 + threadIdx.x;
  if (idx >= QKVN * EMBED) return;
  int n = idx / EMBED, k = idx - n * EMBED;
  float val = 0.f;
  if (n < 1134) {
    int type = n / 378, rem = n - type * 378;
    int h = rem / HSZ, hs = rem - h * HSZ;
    const float* W = (type == 0) ? wq : (type == 1) ? wk : wv;
    val = W[((size_t)h * EMBED + k) * HSZ + hs];
  }
  wt[idx] = f2bf(val);
  if (idx < QKVN) {
    float bval = 0.f;
    if (idx < 1134) {
      int type = idx / 378, rem = idx - type * 378;
      int h = rem / HSZ, hs = rem - h * HSZ;
      const float* B = (type == 0) ? bq : (type == 1) ? bk : bv;
      bval = B[h * HSZ + hs];
    }
    bqkv[idx] = bval;
  }
}

__global__ __launch_bounds__(256) void conv_wot(const float* __restrict__ wo,
    ushort* __restrict__ wt) {
  int idx = blockIdx.x * 256 + threadIdx.x;
  if (idx >= EMBED * EMBED) return;
  int n = idx / EMBED, k = idx - n * EMBED;
  wt[idx] = f2bf((k < 378) ? wo[(size_t)k * EMBED + n] : 0.f);
}

__global__ __launch_bounds__(256) void convT_kernel(const float* __restrict__ in,
    ushort* __restrict__ out, int K, int N) {
  int idx = blockIdx.x * 256 + threadIdx.x;
  if (idx >= N * K) return;
  int n = idx / K, k = idx - n * K;
  out[idx] = f2bf(in[(size_t)k * N + n]);
}

__global__ __launch_bounds__(256) void pad_aout_kernel(ushort* __restrict__ aout) {
  int idx = blockIdx.x * 256 + threadIdx.x;
  if (idx >= NTOK * 6) return;
  int row = idx / 6, c = idx - row * 6;
  aout[(size_t)row * EMBED + 378 + c] = 0;
}

// ---------------- MFMA flash attention ----------------
// qkv: [NTOK][1152] bf16 (q at h*54, k at 378+h*54, v at 756+h*54)
// o:   [NTOK][384] bf16 at col h*54
// grid (SEQ/64, BATCH*HEADS), 256 threads = 4 waves, wave w owns q-rows w*16..w*16+15.
// S^T = mfma(K,Q) so P stays lane-local as the B-operand of O^T = mfma(V^T, P).
// Key->slot permutation: key k = 32m+16b+4g+r  <->  slot 32m+8g+4b+r.
__global__ __launch_bounds__(256) void attn_mfma_kernel(const ushort* __restrict__ qkv,
    ushort* __restrict__ o) {
  __shared__ ushort Qs[64 * AST];
  __shared__ ushort Ks[64 * AST];
  __shared__ ushort Vt[64 * AST];   // [d][slot], col XOR-swizzled by (d&7)<<3
  int tid = threadIdx.x;
  int bh = blockIdx.y;
  int b = bh / HEADS, h = bh - b * HEADS;
  int qt = blockIdx.x;
  int w = tid >> 6, l = tid & 63;
  int lr = l & 15, lg = l >> 4;
  const ushort* base = qkv + (size_t)b * SEQ * QKVN + h * HSZ;

  // zero contraction pads d=54..63 of Q,K (dwords 27..31 of each row)
  for (int e = tid; e < 64 * 5; e += 256) {
    int r = e / 5, c = e - r * 5;
    *reinterpret_cast<uint*>(&Qs[r * AST + 54 + c * 2]) = 0;
    *reinterpret_cast<uint*>(&Ks[r * AST + 54 + c * 2]) = 0;
  }
  // stage Q tile (rows qt*64 + r)
  for (int e = tid; e < 64 * 27; e += 256) {
    int r = e / 27, c = e - r * 27;
    uint u = *reinterpret_cast<const uint*>(base + (size_t)(qt * 64 + r) * QKVN + 2 * c);
    *reinterpret_cast<uint*>(&Qs[r * AST + 2 * c]) = u;
  }
  __syncthreads();
  s16x8 qf[2];  // B-frag: Q[q=w*16+lr][32h2 + 8lg + j]
  qf[0] = *reinterpret_cast<const s16x8*>(&Qs[(w * 16 + lr) * AST + 8 * lg]);
  qf[1] = *reinterpret_cast<const s16x8*>(&Qs[(w * 16 + lr) * AST + 32 + 8 * lg]);

  int qglob = qt * 64 + w * 16 + lr;
  float mrow = -1e30f, lrow = 0.f;
  f32x4 acc[4];   // O^T frags: C[d = dblk*16 + 4lg + r][q = lr]
#pragma unroll
  for (int d = 0; d < 4; ++d) acc[d] = (f32x4){0.f, 0.f, 0.f, 0.f};

  for (int kt = 0; kt <= qt; ++kt) {
    __syncthreads();  // prev tile fully consumed
    for (int e = tid; e < 64 * 27; e += 256) {
      int k = e / 27, c = e - k * 27;
      size_t row = (size_t)(kt * 64 + k) * QKVN;
      *reinterpret_cast<uint*>(&Ks[k * AST + 2 * c]) =
          *reinterpret_cast<const uint*>(base + 378 + row + 2 * c);
      uint uv = *reinterpret_cast<const uint*>(base + 756 + row + 2 * c);
      int s = ((k >> 5) << 5) | (((k >> 2) & 3) << 3) | (((k >> 4) & 1) << 2) | (k & 3);
      int d0 = 2 * c, d1 = 2 * c + 1;
      Vt[d0 * AST + (s ^ ((d0 & 7) << 3))] = (ushort)(uv & 0xffffu);
      Vt[d1 * AST + (s ^ ((d1 & 7) << 3))] = (ushort)(uv >> 16);
    }
    __syncthreads();
    // S^T = K @ Q^T : C[key=16kb+4lg+r][q=lr]
    f32x4 sacc[4];
#pragma unroll
    for (int kb = 0; kb < 4; ++kb) {
      sacc[kb] = (f32x4){0.f, 0.f, 0.f, 0.f};
#pragma unroll
      for (int h2 = 0; h2 < 2; ++h2) {
        s16x8 kf = *reinterpret_cast<const s16x8*>(&Ks[(kb * 16 + lr) * AST + 32 * h2 + 8 * lg]);
        sacc[kb] = __builtin_amdgcn_mfma_f32_16x16x32_bf16(kf, qf[h2], sacc[kb], 0, 0, 0);
      }
    }
    // scale + causal mask + online softmax (q = lr is lane-local everywhere)
    float sv[4][4];
    float mt = -1e30f;
    bool diag = (kt == qt);
#pragma unroll
    for (int kb = 0; kb < 4; ++kb)
#pragma unroll
      for (int r = 0; r < 4; ++r) {
        float s = sacc[kb][r] * SCALE;
        if (diag && (kt * 64 + kb * 16 + 4 * lg + r) > qglob) s = -1e30f;
        sv[kb][r] = s;
        mt = fmaxf(mt, s);
      }
    mt = fmaxf(mt, __shfl_xor(mt, 16));
    mt = fmaxf(mt, __shfl_xor(mt, 32));
    float mnew = fmaxf(mrow, mt);
    float al = __expf(mrow - mnew);
    float lsum = 0.f;
    short p16[4][4];
#pragma unroll
    for (int kb = 0; kb < 4; ++kb)
#pragma unroll
      for (int r = 0; r < 4; ++r) {
        float p = __expf(sv[kb][r] - mnew);
        lsum += p;
        p16[kb][r] = (short)f2bf(p);
      }
    lsum += __shfl_xor(lsum, 16);
    lsum += __shfl_xor(lsum, 32);
    lrow = lrow * al + lsum;
    mrow = mnew;
#pragma unroll
    for (int d = 0; d < 4; ++d)
#pragma unroll
      for (int r = 0; r < 4; ++r) acc[d][r] *= al;
    // P as B-frag: af[m][j] = P[q=lr][slot 8lg+j]  (slot->key matches Vt staging)
    s16x8 af[2];
#pragma unroll
    for (int m = 0; m < 2; ++m)
#pragma unroll
      for (int j = 0; j < 8; ++j) af[m][j] = p16[2 * m + (j >> 2)][j & 3];
    // O^T += V^T @ P^T : A-frag = Vt rows d=dblk*16+lr, slots 32m+8lg.. (swizzled)
#pragma unroll
    for (int m = 0; m < 2; ++m)
#pragma unroll
      for (int d = 0; d < 4; ++d) {
        int row = d * 16 + lr;
        int col = (32 * m + 8 * lg) ^ ((row & 7) << 3);
        s16x8 vf = *reinterpret_cast<const s16x8*>(&Vt[row * AST + col]);
        acc[d] = __builtin_amdgcn_mfma_f32_16x16x32_bf16(vf, af[m], acc[d], 0, 0, 0);
      }
  }

  float linv = 1.f / lrow;
  __syncthreads();
  ushort* Olds = Ks;  // reuse: [d][q]
#pragma unroll
  for (int d = 0; d < 4; ++d)
#pragma unroll
    for (int r = 0; r < 4; ++r)
      Olds[(d * 16 + 4 * lg + r) * AST + w * 16 + lr] = f2bf(acc[d][r] * linv);
  __syncthreads();
  for (int e = tid; e < 64 * 27; e += 256) {
    int q = e / 27, c = e - q * 27;
    uint lo = Olds[(2 * c) * AST + q];
    uint hi = Olds[(2 * c + 1) * AST + q];
    *reinterpret_cast<uint*>(&o[(size_t)(b * SEQ + qt * 64 + q) * EMBED + h * HSZ + 2 * c]) =
        lo | (hi << 16);
  }
}

// ---------------- bf16 MFMA GEMM (m97 structure: 128x128 tile, BK=64, 4 waves) ----------------
// MODE 0: C = bf16(A@B + bias)   MODE 1: C = bf16(gelu(A@B + bias))   MODE 2: C = f32(A@B+bias+resid)
template<int KSTEPS, int LDA, int LDB, int MODE>
__global__ __launch_bounds__(256) void mfma_gemm(
    const char* __restrict__ Ab, const char* __restrict__ Btb,
    const float* __restrict__ bias, const float* __restrict__ resid,
    char* __restrict__ Cb, int ncols) {
  __shared__ ushort As[8192];
  __shared__ ushort Bs[8192];
  int tid = threadIdx.x;
  int wv = tid >> 6, l = tid & 63;
  int wr = wv >> 1, wc = wv & 1;
  int lr = l & 15, lg = l >> 4;
  int tok0 = blockIdx.x << 7;
  int col0 = blockIdx.y << 7;

  const char* aptr[4]; const char* bptr[4];
#pragma unroll
  for (int is = 0; is < 4; ++is) {
    int i = is * 256 + tid;
    int row = i >> 3;
    int boff = (i & 7) << 4;
    int sw = boff ^ ((row & 7) << 4);
    aptr[is] = Ab + (size_t)(tok0 + row) * LDA + sw;
    bptr[is] = Btb + (size_t)(col0 + row) * LDB + sw;
  }

  int offA[2][4], offB[2][4];
#pragma unroll
  for (int m = 0; m < 4; ++m) {
    int rowa = wr * 64 + m * 16 + lr;
    int rowb = wc * 64 + m * 16 + lr;
    int sa = (rowa & 7) << 4, sb = (rowb & 7) << 4;
#pragma unroll
    for (int kk = 0; kk < 2; ++kk) {
      int kb = kk * 64 + lg * 16;
      offA[kk][m] = (rowa * 128 + (kb ^ sa)) >> 1;
      offB[kk][m] = (rowb * 128 + (kb ^ sb)) >> 1;
    }
  }

  f32x4 acc[4][4];
#pragma unroll
  for (int m = 0; m < 4; ++m)
#pragma unroll
    for (int n = 0; n < 4; ++n) acc[m][n] = (f32x4){0.f, 0.f, 0.f, 0.f};

  for (int ks = 0; ks < KSTEPS; ++ks) {
#pragma unroll
    for (int is = 0; is < 4; ++is) {
      gload16(aptr[is] + ks * 128, (char*)As + is * 4096 + wv * 1024);
      gload16(bptr[is] + ks * 128, (char*)Bs + is * 4096 + wv * 1024);
    }
    __syncthreads();
#pragma unroll
    for (int kk = 0; kk < 2; ++kk) {
      s16x8 af[4], bfr[4];
#pragma unroll
      for (int m = 0; m < 4; ++m) af[m] = *reinterpret_cast<const s16x8*>(&As[offA[kk][m]]);
#pragma unroll
      for (int n = 0; n < 4; ++n) bfr[n] = *reinterpret_cast<const s16x8*>(&Bs[offB[kk][n]]);
#pragma unroll
      for (int m = 0; m < 4; ++m)
#pragma unroll
        for (int n = 0; n < 4; ++n)
          acc[m][n] = __builtin_amdgcn_mfma_f32_16x16x32_bf16(af[m], bfr[n], acc[m][n], 0, 0, 0);
    }
    __syncthreads();
  }

  int tokr = tok0 + wr * 64 + lg * 4;
  int colr = col0 + wc * 64 + lr;
  float bn[4];
#pragma unroll
  for (int n = 0; n < 4; ++n) bn[n] = bias[colr + n * 16];
  if constexpr (MODE == 2) {
    float* C = (float*)Cb;
#pragma unroll
    for (int m = 0; m < 4; ++m)
#pragma unroll
      for (int r = 0; r < 4; ++r) {
        size_t rowbase = (size_t)(tokr + m * 16 + r) * ncols;
#pragma unroll
        for (int n = 0; n < 4; ++n) {
          size_t idx = rowbase + colr + n * 16;
          C[idx] = acc[m][n][r] + bn[n] + resid[idx];
        }
      }
  } else {
    ushort* C = (ushort*)Cb;
#pragma unroll
    for (int m = 0; m < 4; ++m)
#pragma unroll
      for (int r = 0; r < 4; ++r) {
        size_t rowbase = (size_t)(tokr + m * 16 + r) * ncols;
#pragma unroll
        for (int n = 0; n < 4; ++n) {
          float xg = acc[m][n][r] + bn[n];
          if constexpr (MODE == 1)
            xg = 0.5f * xg * (1.f + erff(xg * 0.70710678118654752f));
          C[rowbase + colr + n * 16] = f2bf(xg);
        }
      }
  }
}

extern "C" void kernel_launch(void* const* d_in, const int* in_sizes, int n_in,
                              void* d_out, int out_size, void* d_ws, size_t ws_size,
                              hipStream_t stream) {
  const float* x    = (const float*)d_in[0];
  const float* wq   = (const float*)d_in[1];
  const float* bq   = (const float*)d_in[2];
  const float* wk   = (const float*)d_in[3];
  const float* bk   = (const float*)d_in[4];
  const float* wv   = (const float*)d_in[5];
  const float* bv   = (const float*)d_in[6];
  const float* wo   = (const float*)d_in[7];
  const float* bo   = (const float*)d_in[8];
  const float* w1   = (const float*)d_in[9];
  const float* b1   = (const float*)d_in[10];
  const float* w2   = (const float*)d_in[11];
  const float* b2   = (const float*)d_in[12];
  const float* ln1g = (const float*)d_in[13];
  const float* ln1b = (const float*)d_in[14];
  const float* ln2g = (const float*)d_in[15];
  const float* ln2b = (const float*)d_in[16];
  float* out = (float*)d_out;

  char* wsb = (char*)d_ws;
  float*  x1    = (float*)wsb;
  ushort* ffnb  = (ushort*)(wsb + 50331648);
  ushort* hb    = (ushort*)(wsb + 50331648);
  ushort* qkvb  = (ushort*)(wsb + 75497472);
  ushort* aout  = (ushort*)(wsb + 150994944);
  ushort* h2b   = (ushort*)(wsb + 201326592);
  ushort* w1t   = (ushort*)(wsb + 226492416);
  ushort* w2t   = (ushort*)(wsb + 228261888);
  ushort* wqkvt = (ushort*)(wsb + 230031360);
  ushort* wot   = (ushort*)(wsb + 230916096);
  float*  bqkv  = (float*)(wsb + 231211008);

  conv_qkvw  <<<(QKVN * EMBED + 255) / 256, 256, 0, stream>>>(wq, wk, wv, bq, bk, bv, wqkvt, bqkv);
  conv_wot   <<<(EMBED * EMBED + 255) / 256, 256, 0, stream>>>(wo, wot);
  convT_kernel<<<(EMBED * FFND + 255) / 256, 256, 0, stream>>>(w1, w1t, EMBED, FFND);
  convT_kernel<<<(EMBED * FFND + 255) / 256, 256, 0, stream>>>(w2, w2t, FFND, EMBED);
  pad_aout_kernel<<<(NTOK * 6 + 255) / 256, 256, 0, stream>>>(aout);

  ln_bf16_kernel<<<NTOK / 4, 256, 0, stream>>>(x, ln1g, ln1b, hb);
  mfma_gemm<EMBED / 64, EMBED * 2, EMBED * 2, 0>
      <<<dim3(NTOK / 128, QKVN / 128), 256, 0, stream>>>(
      (const char*)hb, (const char*)wqkvt, bqkv, nullptr, (char*)qkvb, QKVN);
  attn_mfma_kernel<<<dim3(SEQ / 64, BATCH * HEADS), 256, 0, stream>>>(qkvb, aout);
  mfma_gemm<EMBED / 64, EMBED * 2, EMBED * 2, 2>
      <<<dim3(NTOK / 128, EMBED / 128), 256, 0, stream>>>(
      (const char*)aout, (const char*)wot, bo, x, (char*)x1, EMBED);
  ln_bf16_kernel<<<NTOK / 4, 256, 0, stream>>>(x1, ln2g, ln2b, h2b);
  mfma_gemm<EMBED / 64, EMBED * 2, EMBED * 2, 1>
      <<<dim3(NTOK / 128, FFND / 128), 256, 0, stream>>>(
      (const char*)h2b, (const char*)w1t, b1, nullptr, (char*)ffnb, FFND);
  mfma_gemm<FFND / 64, FFND * 2, FFND * 2, 2>
      <<<dim3(NTOK / 128, EMBED / 128), 256, 0, stream>>>(
      (const char*)ffnb, (const char*)w2t, b2, x1, (char*)out, EMBED);
}

// Round 5
// 501.024 us; speedup vs baseline: 29.9857x; 1.0517x over previous
//
#include <hip/hip_runtime.h>
#include <hip/hip_bf16.h>
#include <cmath>

#define BATCH 64
#define SEQ   512
#define EMBED 384
#define HEADS 7
#define HSZ   54
#define FFND  2304
#define NTOK  (BATCH*SEQ)
#define QKVN  1152   // 3*378 padded to 9*128
#define EPS   1e-5f
#define SCALE 0.13608276348795434f  // 54^-0.5

typedef __attribute__((ext_vector_type(8))) short s16x8;
typedef __attribute__((ext_vector_type(4))) float f32x4;

__device__ __forceinline__ ushort f2bf(float f) {
  __hip_bfloat16 h = __float2bfloat16(f);
  return *reinterpret_cast<ushort*>(&h);
}

__device__ __forceinline__ void gload16(const void* g, void* l) {
  __builtin_amdgcn_global_load_lds((const __attribute__((address_space(1))) void*)g,
                                   (__attribute__((address_space(3))) void*)l, 16, 0, 0);
}

// ---------------- LayerNorm -> bf16 out, one wave per row ----------------
__global__ __launch_bounds__(256) void ln_bf16_kernel(const float* __restrict__ x,
    const float* __restrict__ g, const float* __restrict__ b, ushort* __restrict__ out) {
  int wave = threadIdx.x >> 6, lane = threadIdx.x & 63;
  int row = (blockIdx.x << 2) + wave;
  const float* xr = x + (size_t)row * EMBED;
  float v[6]; float s = 0.f;
#pragma unroll
  for (int i = 0; i < 6; ++i) { v[i] = xr[lane + (i << 6)]; s += v[i]; }
#pragma unroll
  for (int off = 32; off; off >>= 1) s += __shfl_xor(s, off);
  float mu = s * (1.f / EMBED);
  float var = 0.f;
#pragma unroll
  for (int i = 0; i < 6; ++i) { float d = v[i] - mu; var += d * d; }
#pragma unroll
  for (int off = 32; off; off >>= 1) var += __shfl_xor(var, off);
  float rstd = rsqrtf(var * (1.f / EMBED) + EPS);
  ushort* orow = out + (size_t)row * EMBED;
#pragma unroll
  for (int i = 0; i < 6; ++i) {
    int c = lane + (i << 6);
    orow[c] = f2bf((v[i] - mu) * rstd * g[c] + b[c]);
  }
}

// ---------------- weight prep kernels ----------------
__global__ __launch_bounds__(256) void conv_qkvw(const float* __restrict__ wq,
    const float* __restrict__ wk, const float* __restrict__ wv,
    const float* __restrict__ bq, const float* __restrict__ bk, const float* __restrict__ bv,
    ushort* __restrict__ wt, float* __restrict__ bqkv) {
  int idx = blockIdx.x * 256 + threadIdx.x;
  if (idx >= QKVN * EMBED) return;
  int n = idx / EMBED, k = idx - n * EMBED;
  float val = 0.f;
  if (n < 1134) {
    int type = n / 378, rem = n - type * 378;
    int h = rem / HSZ, hs = rem - h * HSZ;
    const float* W = (type == 0) ? wq : (type == 1) ? wk : wv;
    val = W[((size_t)h * EMBED + k) * HSZ + hs];
  }
  wt[idx] = f2bf(val);
  if (idx < QKVN) {
    float bval = 0.f;
    if (idx < 1134) {
      int type = idx / 378, rem = idx - type * 378;
      int h = rem / HSZ, hs = rem - h * HSZ;
      const float* B = (type == 0) ? bq : (type == 1) ? bk : bv;
      bval = B[h * HSZ + hs];
    }
    bqkv[idx] = bval;
  }
}

__global__ __launch_bounds__(256) void conv_wot(const float* __restrict__ wo,
    ushort* __restrict__ wt) {
  int idx = blockIdx.x * 256 + threadIdx.x;
  if (idx >= EMBED * EMBED) return;
  int n = idx / EMBED, k = idx - n * EMBED;
  wt[idx] = f2bf((k < 378) ? wo[(size_t)k * EMBED + n] : 0.f);
}

__global__ __launch_bounds__(256) void convT_kernel(const float* __restrict__ in,
    ushort* __restrict__ out, int K, int N) {
  int idx = blockIdx.x * 256 + threadIdx.x;
  if (idx >= N * K) return;
  int n = idx / K, k = idx - n * K;
  out[idx] = f2bf(in[(size_t)k * N + n]);
}

__global__ __launch_bounds__(256) void pad_aout_kernel(ushort* __restrict__ aout) {
  int idx = blockIdx.x * 256 + threadIdx.x;
  if (idx >= NTOK * 6) return;
  int row = idx / 6, c = idx - row * 6;
  aout[(size_t)row * EMBED + 378 + c] = 0;
}

// ---------------- MFMA flash attention (stride-64 swizzled LDS, dbuf pipeline) ----------------
// qkv: [NTOK][1152] bf16 (q at h*54, k at 378+h*54, v at 756+h*54); o: [NTOK][384] bf16
// grid (SEQ/64, BATCH*HEADS), 4 waves; wave w owns q-rows w*16..w*16+15.
// S^T = mfma(K,Q): C[key=16kb+4lg+r][q=lr]; P lane-local -> B-frag of O^T = mfma(V^T,P).
// slot perm: key k = 32m+16b+4g+r <-> slot 32m+8g+4b+r.
// All LDS rows: 64 ushorts, col XOR-swizzled by ((row&7)<<3)  -> conflict-free b128 frag reads.
__global__ __launch_bounds__(256) void attn_mfma_kernel(const ushort* __restrict__ qkv,
    ushort* __restrict__ o) {
  __shared__ ushort Qs[4096];
  __shared__ ushort Ks[2][4096];
  __shared__ ushort Vt[2][4096];   // [d][slot]
  int tid = threadIdx.x;
  int bh = blockIdx.y;
  int b = bh / HEADS, h = bh - b * HEADS;
  int qt = blockIdx.x;
  int qr0 = qt << 6;
  int w = tid >> 6, l = tid & 63;
  int lr = l & 15, lg = l >> 4;
  const ushort* base = qkv + (size_t)b * SEQ * QKVN + h * HSZ;

  // zero the (swizzled images of) pad cols 54..63 in Qs and both Ks buffers
  for (int e = tid; e < 64 * 5; e += 256) {
    int r = e / 5, c = 54 + 2 * (e - r * 5);
    int col = c ^ ((r & 7) << 3);
    *reinterpret_cast<uint*>(&Qs[r * 64 + col]) = 0;
    *reinterpret_cast<uint*>(&Ks[0][r * 64 + col]) = 0;
    *reinterpret_cast<uint*>(&Ks[1][r * 64 + col]) = 0;
  }
  // stage Q + tile 0 of K/V directly
#pragma unroll
  for (int i = 0; i < 7; ++i) {
    int e = tid + i * 256;
    int r = e / 28, c = e - r * 28;
    if (c < 27)
      *reinterpret_cast<uint*>(&Qs[r * 64 + ((2 * c) ^ ((r & 7) << 3))]) =
          *reinterpret_cast<const uint*>(base + (size_t)(qr0 + r) * QKVN + 2 * c);
  }
#pragma unroll
  for (int i = 0; i < 7; ++i) {
    int e = tid + i * 256;
    int k = e / 28, c = e - k * 28;
    if (c < 27)
      *reinterpret_cast<uint*>(&Ks[0][k * 64 + ((2 * c) ^ ((k & 7) << 3))]) =
          *reinterpret_cast<const uint*>(base + 378 + (size_t)k * QKVN + 2 * c);
    int ev = e >> 1, par = e & 1;
    int p = ev / 28, cv = ev - p * 28;
    uint u = (cv < 27) ? *reinterpret_cast<const uint*>(base + 756 + (size_t)(2 * p + par) * QKVN + 2 * cv) : 0u;
    uint uo = __shfl_xor(u, 1);
    if (cv < 27) {
      int k0 = 2 * p;
      int s0 = ((k0 >> 5) << 5) | (((k0 >> 2) & 3) << 3) | (((k0 >> 4) & 1) << 2) | (k0 & 3);
      int d = 2 * cv + par;
      uint wv2 = par ? ((uo >> 16) | (u & 0xffff0000u)) : ((u & 0xffffu) | (uo << 16));
      *reinterpret_cast<uint*>(&Vt[0][d * 64 + (s0 ^ ((d & 7) << 3))]) = wv2;
    }
  }
  __syncthreads();

  int qrow = w * 16 + lr;
  s16x8 qf[2];
  qf[0] = *reinterpret_cast<const s16x8*>(&Qs[qrow * 64 + ((8 * lg) ^ ((qrow & 7) << 3))]);
  qf[1] = *reinterpret_cast<const s16x8*>(&Qs[qrow * 64 + ((32 + 8 * lg) ^ ((qrow & 7) << 3))]);

  int qglob = qr0 + qrow;
  float mrow = -1e30f, lrow = 0.f;
  f32x4 acc[4];
#pragma unroll
  for (int d = 0; d < 4; ++d) acc[d] = (f32x4){0.f, 0.f, 0.f, 0.f};

  uint kreg[7], vreg[7];
  for (int kt = 0; kt <= qt; ++kt) {
    int cur = kt & 1;
    // issue next tile's global reads (latency hidden under compute)
    if (kt < qt) {
#pragma unroll
      for (int i = 0; i < 7; ++i) {
        int e = tid + i * 256;
        int k = e / 28, c = e - k * 28;
        kreg[i] = (c < 27) ? *reinterpret_cast<const uint*>(
            base + 378 + (size_t)((kt + 1) * 64 + k) * QKVN + 2 * c) : 0u;
        int ev = e >> 1, par = e & 1;
        int p = ev / 28, cv = ev - p * 28;
        vreg[i] = (cv < 27) ? *reinterpret_cast<const uint*>(
            base + 756 + (size_t)((kt + 1) * 64 + 2 * p + par) * QKVN + 2 * cv) : 0u;
      }
    }
    // S^T = K @ Q^T
    f32x4 sacc[4];
#pragma unroll
    for (int kb = 0; kb < 4; ++kb) {
      sacc[kb] = (f32x4){0.f, 0.f, 0.f, 0.f};
#pragma unroll
      for (int h2 = 0; h2 < 2; ++h2) {
        int row = kb * 16 + lr;
        s16x8 kf = *reinterpret_cast<const s16x8*>(
            &Ks[cur][row * 64 + ((32 * h2 + 8 * lg) ^ ((row & 7) << 3))]);
        sacc[kb] = __builtin_amdgcn_mfma_f32_16x16x32_bf16(kf, qf[h2], sacc[kb], 0, 0, 0);
      }
    }
    // scale + causal + online softmax (q = lr lane-local)
    float sv[4][4];
    float mt = -1e30f;
    bool diag = (kt == qt);
#pragma unroll
    for (int kb = 0; kb < 4; ++kb)
#pragma unroll
      for (int r = 0; r < 4; ++r) {
        float s = sacc[kb][r] * SCALE;
        if (diag && (kt * 64 + kb * 16 + 4 * lg + r) > qglob) s = -1e30f;
        sv[kb][r] = s;
        mt = fmaxf(mt, s);
      }
    mt = fmaxf(mt, __shfl_xor(mt, 16));
    mt = fmaxf(mt, __shfl_xor(mt, 32));
    float mnew = fmaxf(mrow, mt);
    float al = __expf(mrow - mnew);
    float lsum = 0.f;
    short p16[4][4];
#pragma unroll
    for (int kb = 0; kb < 4; ++kb)
#pragma unroll
      for (int r = 0; r < 4; ++r) {
        float p = __expf(sv[kb][r] - mnew);
        lsum += p;
        p16[kb][r] = (short)f2bf(p);
      }
    lsum += __shfl_xor(lsum, 16);
    lsum += __shfl_xor(lsum, 32);
    lrow = lrow * al + lsum;
    mrow = mnew;
#pragma unroll
    for (int d = 0; d < 4; ++d)
#pragma unroll
      for (int r = 0; r < 4; ++r) acc[d][r] *= al;
    // P as B-frag (slot-permuted), V^T A-frags from LDS
    s16x8 af[2];
#pragma unroll
    for (int m = 0; m < 2; ++m)
#pragma unroll
      for (int j = 0; j < 8; ++j) af[m][j] = p16[2 * m + (j >> 2)][j & 3];
#pragma unroll
    for (int m = 0; m < 2; ++m)
#pragma unroll
      for (int d = 0; d < 4; ++d) {
        int row = d * 16 + lr;
        s16x8 vf = *reinterpret_cast<const s16x8*>(
            &Vt[cur][row * 64 + ((32 * m + 8 * lg) ^ ((row & 7) << 3))]);
        acc[d] = __builtin_amdgcn_mfma_f32_16x16x32_bf16(vf, af[m], acc[d], 0, 0, 0);
      }
    // commit next tile regs -> other buffer; single barrier per tile
    if (kt < qt) {
      __syncthreads();  // everyone done reading buf[cur^1] (tile kt-1) and buf[cur]
      int nxt = cur ^ 1;
#pragma unroll
      for (int i = 0; i < 7; ++i) {
        int e = tid + i * 256;
        int k = e / 28, c = e - k * 28;
        if (c < 27)
          *reinterpret_cast<uint*>(&Ks[nxt][k * 64 + ((2 * c) ^ ((k & 7) << 3))]) = kreg[i];
        int ev = e >> 1, par = e & 1;
        int p = ev / 28, cv = ev - p * 28;
        uint u = vreg[i];
        uint uo = __shfl_xor(u, 1);
        if (cv < 27) {
          int k0 = 2 * p;
          int s0 = ((k0 >> 5) << 5) | (((k0 >> 2) & 3) << 3) | (((k0 >> 4) & 1) << 2) | (k0 & 3);
          int d = 2 * cv + par;
          uint wv2 = par ? ((uo >> 16) | (u & 0xffff0000u)) : ((u & 0xffffu) | (uo << 16));
          *reinterpret_cast<uint*>(&Vt[nxt][d * 64 + (s0 ^ ((d & 7) << 3))]) = wv2;
        }
      }
      __syncthreads();  // buf[nxt] ready for next iteration
    }
  }

  float linv = 1.f / lrow;
  ushort* Olds = Qs;  // reuse: [d][q], stride 64
#pragma unroll
  for (int d = 0; d < 4; ++d)
#pragma unroll
    for (int r = 0; r < 4; ++r)
      Olds[(d * 16 + 4 * lg + r) * 64 + w * 16 + lr] = f2bf(acc[d][r] * linv);
  __syncthreads();
  for (int e = tid; e < 64 * 27; e += 256) {
    int q = e / 27, c = e - q * 27;
    uint lo = Olds[(2 * c) * 64 + q];
    uint hi = Olds[(2 * c + 1) * 64 + q];
    *reinterpret_cast<uint*>(&o[(size_t)(b * SEQ + qr0 + q) * EMBED + h * HSZ + 2 * c]) =
        lo | (hi << 16);
  }
}

// ---------------- bf16 MFMA GEMM (m97 structure: 128x128 tile, BK=64, 4 waves) ----------------
// MODE 0: C = bf16(A@B + bias)   MODE 1: C = bf16(gelu(A@B + bias))   MODE 2: C = f32(A@B+bias+resid)
template<int KSTEPS, int LDA, int LDB, int MODE>
__global__ __launch_bounds__(256) void mfma_gemm(
    const char* __restrict__ Ab, const char* __restrict__ Btb,
    const float* __restrict__ bias, const float* __restrict__ resid,
    char* __restrict__ Cb, int ncols) {
  __shared__ ushort As[8192];
  __shared__ ushort Bs[8192];
  int tid = threadIdx.x;
  int wv = tid >> 6, l = tid & 63;
  int wr = wv >> 1, wc = wv & 1;
  int lr = l & 15, lg = l >> 4;
  int tok0 = blockIdx.x << 7;
  int col0 = blockIdx.y << 7;

  const char* aptr[4]; const char* bptr[4];
#pragma unroll
  for (int is = 0; is < 4; ++is) {
    int i = is * 256 + tid;
    int row = i >> 3;
    int boff = (i & 7) << 4;
    int sw = boff ^ ((row & 7) << 4);
    aptr[is] = Ab + (size_t)(tok0 + row) * LDA + sw;
    bptr[is] = Btb + (size_t)(col0 + row) * LDB + sw;
  }

  int offA[2][4], offB[2][4];
#pragma unroll
  for (int m = 0; m < 4; ++m) {
    int rowa = wr * 64 + m * 16 + lr;
    int rowb = wc * 64 + m * 16 + lr;
    int sa = (rowa & 7) << 4, sb = (rowb & 7) << 4;
#pragma unroll
    for (int kk = 0; kk < 2; ++kk) {
      int kb = kk * 64 + lg * 16;
      offA[kk][m] = (rowa * 128 + (kb ^ sa)) >> 1;
      offB[kk][m] = (rowb * 128 + (kb ^ sb)) >> 1;
    }
  }

  f32x4 acc[4][4];
#pragma unroll
  for (int m = 0; m < 4; ++m)
#pragma unroll
    for (int n = 0; n < 4; ++n) acc[m][n] = (f32x4){0.f, 0.f, 0.f, 0.f};

  for (int ks = 0; ks < KSTEPS; ++ks) {
#pragma unroll
    for (int is = 0; is < 4; ++is) {
      gload16(aptr[is] + ks * 128, (char*)As + is * 4096 + wv * 1024);
      gload16(bptr[is] + ks * 128, (char*)Bs + is * 4096 + wv * 1024);
    }
    __syncthreads();
#pragma unroll
    for (int kk = 0; kk < 2; ++kk) {
      s16x8 af[4], bfr[4];
#pragma unroll
      for (int m = 0; m < 4; ++m) af[m] = *reinterpret_cast<const s16x8*>(&As[offA[kk][m]]);
#pragma unroll
      for (int n = 0; n < 4; ++n) bfr[n] = *reinterpret_cast<const s16x8*>(&Bs[offB[kk][n]]);
#pragma unroll
      for (int m = 0; m < 4; ++m)
#pragma unroll
        for (int n = 0; n < 4; ++n)
          acc[m][n] = __builtin_amdgcn_mfma_f32_16x16x32_bf16(af[m], bfr[n], acc[m][n], 0, 0, 0);
    }
    __syncthreads();
  }

  int tokr = tok0 + wr * 64 + lg * 4;
  int colr = col0 + wc * 64 + lr;
  float bn[4];
#pragma unroll
  for (int n = 0; n < 4; ++n) bn[n] = bias[colr + n * 16];
  if constexpr (MODE == 2) {
    float* C = (float*)Cb;
#pragma unroll
    for (int m = 0; m < 4; ++m)
#pragma unroll
      for (int r = 0; r < 4; ++r) {
        size_t rowbase = (size_t)(tokr + m * 16 + r) * ncols;
#pragma unroll
        for (int n = 0; n < 4; ++n) {
          size_t idx = rowbase + colr + n * 16;
          C[idx] = acc[m][n][r] + bn[n] + resid[idx];
        }
      }
  } else {
    ushort* C = (ushort*)Cb;
#pragma unroll
    for (int m = 0; m < 4; ++m)
#pragma unroll
      for (int r = 0; r < 4; ++r) {
        size_t rowbase = (size_t)(tokr + m * 16 + r) * ncols;
#pragma unroll
        for (int n = 0; n < 4; ++n) {
          float xg = acc[m][n][r] + bn[n];
          if constexpr (MODE == 1)
            xg = 0.5f * xg * (1.f + erff(xg * 0.70710678118654752f));
          C[rowbase + colr + n * 16] = f2bf(xg);
        }
      }
  }
}

extern "C" void kernel_launch(void* const* d_in, const int* in_sizes, int n_in,
                              void* d_out, int out_size, void* d_ws, size_t ws_size,
                              hipStream_t stream) {
  const float* x    = (const float*)d_in[0];
  const float* wq   = (const float*)d_in[1];
  const float* bq   = (const float*)d_in[2];
  const float* wk   = (const float*)d_in[3];
  const float* bk   = (const float*)d_in[4];
  const float* wv   = (const float*)d_in[5];
  const float* bv   = (const float*)d_in[6];
  const float* wo   = (const float*)d_in[7];
  const float* bo   = (const float*)d_in[8];
  const float* w1   = (const float*)d_in[9];
  const float* b1   = (const float*)d_in[10];
  const float* w2   = (const float*)d_in[11];
  const float* b2   = (const float*)d_in[12];
  const float* ln1g = (const float*)d_in[13];
  const float* ln1b = (const float*)d_in[14];
  const float* ln2g = (const float*)d_in[15];
  const float* ln2b = (const float*)d_in[16];
  float* out = (float*)d_out;

  char* wsb = (char*)d_ws;
  float*  x1    = (float*)wsb;
  ushort* ffnb  = (ushort*)(wsb + 50331648);
  ushort* hb    = (ushort*)(wsb + 50331648);
  ushort* qkvb  = (ushort*)(wsb + 75497472);
  ushort* aout  = (ushort*)(wsb + 150994944);
  ushort* h2b   = (ushort*)(wsb + 201326592);
  ushort* w1t   = (ushort*)(wsb + 226492416);
  ushort* w2t   = (ushort*)(wsb + 228261888);
  ushort* wqkvt = (ushort*)(wsb + 230031360);
  ushort* wot   = (ushort*)(wsb + 230916096);
  float*  bqkv  = (float*)(wsb + 231211008);

  conv_qkvw  <<<(QKVN * EMBED + 255) / 256, 256, 0, stream>>>(wq, wk, wv, bq, bk, bv, wqkvt, bqkv);
  conv_wot   <<<(EMBED * EMBED + 255) / 256, 256, 0, stream>>>(wo, wot);
  convT_kernel<<<(EMBED * FFND + 255) / 256, 256, 0, stream>>>(w1, w1t, EMBED, FFND);
  convT_kernel<<<(EMBED * FFND + 255) / 256, 256, 0, stream>>>(w2, w2t, FFND, EMBED);
  pad_aout_kernel<<<(NTOK * 6 + 255) / 256, 256, 0, stream>>>(aout);

  ln_bf16_kernel<<<NTOK / 4, 256, 0, stream>>>(x, ln1g, ln1b, hb);
  mfma_gemm<EMBED / 64, EMBED * 2, EMBED * 2, 0>
      <<<dim3(NTOK / 128, QKVN / 128), 256, 0, stream>>>(
      (const char*)hb, (const char*)wqkvt, bqkv, nullptr, (char*)qkvb, QKVN);
  attn_mfma_kernel<<<dim3(SEQ / 64, BATCH * HEADS), 256, 0, stream>>>(qkvb, aout);
  mfma_gemm<EMBED / 64, EMBED * 2, EMBED * 2, 2>
      <<<dim3(NTOK / 128, EMBED / 128), 256, 0, stream>>>(
      (const char*)aout, (const char*)wot, bo, x, (char*)x1, EMBED);
  ln_bf16_kernel<<<NTOK / 4, 256, 0, stream>>>(x1, ln2g, ln2b, h2b);
  mfma_gemm<EMBED / 64, EMBED * 2, EMBED * 2, 1>
      <<<dim3(NTOK / 128, FFND / 128), 256, 0, stream>>>(
      (const char*)h2b, (const char*)w1t, b1, nullptr, (char*)ffnb, FFND);
  mfma_gemm<FFND / 64, FFND * 2, FFND * 2, 2>
      <<<dim3(NTOK / 128, EMBED / 128), 256, 0, stream>>>(
      (const char*)ffnb, (const char*)w2t, b2, x1, (char*)out, EMBED);
}

// Round 6
// 478.697 us; speedup vs baseline: 31.3843x; 1.0466x over previous
//
#include <hip/hip_runtime.h>
#include <hip/hip_bf16.h>
#include <cmath>

#define BATCH 64
#define SEQ   512
#define EMBED 384
#define HEADS 7
#define HSZ   54
#define FFND  2304
#define NTOK  (BATCH*SEQ)
#define QKVN  1152   // 3*378 padded to 9*128
#define EPS   1e-5f
#define SCALE 0.13608276348795434f  // 54^-0.5

typedef __attribute__((ext_vector_type(8))) short s16x8;
typedef __attribute__((ext_vector_type(4))) float f32x4;

__device__ __forceinline__ ushort f2bf(float f) {
  __hip_bfloat16 h = __float2bfloat16(f);
  return *reinterpret_cast<ushort*>(&h);
}

__device__ __forceinline__ void gload16(const void* g, void* l) {
  __builtin_amdgcn_global_load_lds((const __attribute__((address_space(1))) void*)g,
                                   (__attribute__((address_space(3))) void*)l, 16, 0, 0);
}

// ---------------- LayerNorm -> bf16 out, one wave per row ----------------
__global__ __launch_bounds__(256) void ln_bf16_kernel(const float* __restrict__ x,
    const float* __restrict__ g, const float* __restrict__ b, ushort* __restrict__ out) {
  int wave = threadIdx.x >> 6, lane = threadIdx.x & 63;
  int row = (blockIdx.x << 2) + wave;
  const float* xr = x + (size_t)row * EMBED;
  float v[6]; float s = 0.f;
#pragma unroll
  for (int i = 0; i < 6; ++i) { v[i] = xr[lane + (i << 6)]; s += v[i]; }
#pragma unroll
  for (int off = 32; off; off >>= 1) s += __shfl_xor(s, off);
  float mu = s * (1.f / EMBED);
  float var = 0.f;
#pragma unroll
  for (int i = 0; i < 6; ++i) { float d = v[i] - mu; var += d * d; }
#pragma unroll
  for (int off = 32; off; off >>= 1) var += __shfl_xor(var, off);
  float rstd = rsqrtf(var * (1.f / EMBED) + EPS);
  ushort* orow = out + (size_t)row * EMBED;
#pragma unroll
  for (int i = 0; i < 6; ++i) {
    int c = lane + (i << 6);
    orow[c] = f2bf((v[i] - mu) * rstd * g[c] + b[c]);
  }
}

// ---------------- tiled transpose+convert: out[n][k] = bf16(in[k][n]), zero-padded ----------------
// in is [srcK][srcN] f32; out is [N][K] bf16. Coalesced reads and writes via 32x32 LDS tile.
__global__ __launch_bounds__(256) void convT_tiled(const float* __restrict__ in,
    ushort* __restrict__ out, int K, int N, int srcK, int srcN) {
  __shared__ float t[32][33];
  int k0 = blockIdx.x << 5, n0 = blockIdx.y << 5;
  int tx = threadIdx.x & 31, ty = threadIdx.x >> 5;
#pragma unroll
  for (int i = 0; i < 4; ++i) {
    int r = ty + i * 8;
    int k = k0 + r, n = n0 + tx;
    t[r][tx] = (k < srcK && n < srcN) ? in[(size_t)k * srcN + n] : 0.f;
  }
  __syncthreads();
#pragma unroll
  for (int i = 0; i < 4; ++i) {
    int r = ty + i * 8;
    int n = n0 + r, k = k0 + tx;
    if (n < N && k < K) out[(size_t)n * K + k] = f2bf(t[tx][r]);
  }
}

// ---------------- QKV weight pack: wqkvt[n][k], n = type*378 + h*54 + hs ----------------
// grid (12, 2, 21): x = k-tile, y = hs-tile, z = type*7+h
__global__ __launch_bounds__(256) void conv_qkvw_tiled(const float* __restrict__ wq,
    const float* __restrict__ wk, const float* __restrict__ wv, ushort* __restrict__ wt) {
  __shared__ float t[32][33];
  int k0 = blockIdx.x << 5, hs0 = blockIdx.y << 5;
  int z = blockIdx.z, type = z / 7, h = z - type * 7;
  const float* W = (type == 0) ? wq : (type == 1) ? wk : wv;
  int tx = threadIdx.x & 31, ty = threadIdx.x >> 5;
#pragma unroll
  for (int i = 0; i < 4; ++i) {
    int r = ty + i * 8;
    int k = k0 + r, hs = hs0 + tx;
    t[r][tx] = (hs < HSZ) ? W[((size_t)h * EMBED + k) * HSZ + hs] : 0.f;
  }
  __syncthreads();
#pragma unroll
  for (int i = 0; i < 4; ++i) {
    int r = ty + i * 8;
    int hs = hs0 + r, k = k0 + tx;
    if (hs < HSZ) wt[(size_t)(type * 378 + h * HSZ + hs) * EMBED + k0 + tx] = f2bf(t[tx][r]);
  }
}

// ---------------- misc fills: wqkvt pad rows 1134..1151 + bqkv bias vector ----------------
__global__ __launch_bounds__(256) void fill_misc(const float* __restrict__ bq,
    const float* __restrict__ bk, const float* __restrict__ bv,
    ushort* __restrict__ wt, float* __restrict__ bqkv) {
  int idx = blockIdx.x * 256 + threadIdx.x;
  if (idx < 18 * EMBED) wt[1134 * EMBED + idx] = 0;
  if (idx < QKVN) {
    float bval = 0.f;
    if (idx < 1134) {
      int type = idx / 378, rem = idx - type * 378;
      int h = rem / HSZ, hs = rem - h * HSZ;
      const float* B = (type == 0) ? bq : (type == 1) ? bk : bv;
      bval = B[h * HSZ + hs];
    }
    bqkv[idx] = bval;
  }
}

__global__ __launch_bounds__(256) void pad_aout_kernel(ushort* __restrict__ aout) {
  int idx = blockIdx.x * 256 + threadIdx.x;
  if (idx >= NTOK * 6) return;
  int row = idx / 6, c = idx - row * 6;
  aout[(size_t)row * EMBED + 378 + c] = 0;
}

// ---------------- MFMA flash attention ----------------
// 1D grid 3584: id -> xcd=id&7, bh=xcd+8*(id>>6), qt=7-((id>>3)&7).
// Same-bh blocks are temporally adjacent on the SAME XCD (K/V L2 reuse); heavy qt first.
// Q staged into Ks[1] (dead until tile-1 commit, barrier-ordered). LDS 32 KB -> 5 blocks/CU.
// S^T = mfma(K,Q): C[key=16kb+4lg+r][q=lr]; P lane-local -> B-frag of O^T = mfma(V^T,P).
// slot perm: key k = 32m+16b+4g+r <-> slot 32m+8g+4b+r. All LDS rows 64 ushorts,
// col XOR-swizzled by ((row&7)<<3) -> conflict-free b128 frag reads.
__global__ __launch_bounds__(256) void attn_mfma_kernel(const ushort* __restrict__ qkv,
    ushort* __restrict__ o) {
  __shared__ ushort Ks[2][4096];
  __shared__ ushort Vt[2][4096];   // [d][slot]
  int tid = threadIdx.x;
  int id = blockIdx.x;
  int xcd = id & 7;
  int sseq = id >> 3;
  int bh = xcd + 8 * (sseq >> 3);
  int qt = (SEQ / 64 - 1) - (sseq & 7);
  int b = bh / HEADS, h = bh - b * HEADS;
  int qr0 = qt << 6;
  int w = tid >> 6, l = tid & 63;
  int lr = l & 15, lg = l >> 4;
  const ushort* base = qkv + (size_t)b * SEQ * QKVN + h * HSZ;

  // zero pad cols 54..63 of both Ks buffers (Ks[1] pads also serve the Q tile)
  for (int e = tid; e < 64 * 5; e += 256) {
    int r = e / 5, c = 54 + 2 * (e - r * 5);
    int col = c ^ ((r & 7) << 3);
    *reinterpret_cast<uint*>(&Ks[0][r * 64 + col]) = 0;
    *reinterpret_cast<uint*>(&Ks[1][r * 64 + col]) = 0;
  }
  // stage Q -> Ks[1], K0 -> Ks[0], V0 -> Vt[0]
#pragma unroll
  for (int i = 0; i < 7; ++i) {
    int e = tid + i * 256;
    int r = e / 28, c = e - r * 28;
    if (c < 27)
      *reinterpret_cast<uint*>(&Ks[1][r * 64 + ((2 * c) ^ ((r & 7) << 3))]) =
          *reinterpret_cast<const uint*>(base + (size_t)(qr0 + r) * QKVN + 2 * c);
  }
#pragma unroll
  for (int i = 0; i < 7; ++i) {
    int e = tid + i * 256;
    int k = e / 28, c = e - k * 28;
    if (c < 27)
      *reinterpret_cast<uint*>(&Ks[0][k * 64 + ((2 * c) ^ ((k & 7) << 3))]) =
          *reinterpret_cast<const uint*>(base + 378 + (size_t)k * QKVN + 2 * c);
    int ev = e >> 1, par = e & 1;
    int p = ev / 28, cv = ev - p * 28;
    uint u = (cv < 27) ? *reinterpret_cast<const uint*>(base + 756 + (size_t)(2 * p + par) * QKVN + 2 * cv) : 0u;
    uint uo = __shfl_xor(u, 1);
    if (cv < 27) {
      int k0 = 2 * p;
      int s0 = ((k0 >> 5) << 5) | (((k0 >> 2) & 3) << 3) | (((k0 >> 4) & 1) << 2) | (k0 & 3);
      int d = 2 * cv + par;
      uint wv2 = par ? ((uo >> 16) | (u & 0xffff0000u)) : ((u & 0xffffu) | (uo << 16));
      *reinterpret_cast<uint*>(&Vt[0][d * 64 + (s0 ^ ((d & 7) << 3))]) = wv2;
    }
  }
  __syncthreads();

  int qrow = w * 16 + lr;
  s16x8 qf[2];
  qf[0] = *reinterpret_cast<const s16x8*>(&Ks[1][qrow * 64 + ((8 * lg) ^ ((qrow & 7) << 3))]);
  qf[1] = *reinterpret_cast<const s16x8*>(&Ks[1][qrow * 64 + ((32 + 8 * lg) ^ ((qrow & 7) << 3))]);

  int qglob = qr0 + qrow;
  float mrow = -1e30f, lrow = 0.f;   // lrow: per-lane partial (reduced at end)
  f32x4 acc[4];
#pragma unroll
  for (int d = 0; d < 4; ++d) acc[d] = (f32x4){0.f, 0.f, 0.f, 0.f};

  uint kreg[7], vreg[7];
  for (int kt = 0; kt <= qt; ++kt) {
    int cur = kt & 1;
    if (kt < qt) {  // prefetch next tile into regs (hidden under compute)
#pragma unroll
      for (int i = 0; i < 7; ++i) {
        int e = tid + i * 256;
        int k = e / 28, c = e - k * 28;
        kreg[i] = (c < 27) ? *reinterpret_cast<const uint*>(
            base + 378 + (size_t)((kt + 1) * 64 + k) * QKVN + 2 * c) : 0u;
        int ev = e >> 1, par = e & 1;
        int p = ev / 28, cv = ev - p * 28;
        vreg[i] = (cv < 27) ? *reinterpret_cast<const uint*>(
            base + 756 + (size_t)((kt + 1) * 64 + 2 * p + par) * QKVN + 2 * cv) : 0u;
      }
    }
    // S^T = K @ Q^T
    f32x4 sacc[4];
    __builtin_amdgcn_s_setprio(1);
#pragma unroll
    for (int kb = 0; kb < 4; ++kb) {
      sacc[kb] = (f32x4){0.f, 0.f, 0.f, 0.f};
#pragma unroll
      for (int h2 = 0; h2 < 2; ++h2) {
        int row = kb * 16 + lr;
        s16x8 kf = *reinterpret_cast<const s16x8*>(
            &Ks[cur][row * 64 + ((32 * h2 + 8 * lg) ^ ((row & 7) << 3))]);
        sacc[kb] = __builtin_amdgcn_mfma_f32_16x16x32_bf16(kf, qf[h2], sacc[kb], 0, 0, 0);
      }
    }
    __builtin_amdgcn_s_setprio(0);
    // scale + causal + online softmax (q = lr lane-local)
    float sv[4][4];
    float mt = -1e30f;
    bool diag = (kt == qt);
#pragma unroll
    for (int kb = 0; kb < 4; ++kb)
#pragma unroll
      for (int r = 0; r < 4; ++r) {
        float s = sacc[kb][r] * SCALE;
        if (diag && (kt * 64 + kb * 16 + 4 * lg + r) > qglob) s = -1e30f;
        sv[kb][r] = s;
        mt = fmaxf(mt, s);
      }
    mt = fmaxf(mt, __shfl_xor(mt, 16));
    mt = fmaxf(mt, __shfl_xor(mt, 32));
    // defer-max (T13): only rescale when the running max grew by > 8
    if (!__all(mt - mrow <= 8.f)) {
      float mnew = fmaxf(mrow, mt);
      float al = __expf(mrow - mnew);
#pragma unroll
      for (int d = 0; d < 4; ++d)
#pragma unroll
        for (int r = 0; r < 4; ++r) acc[d][r] *= al;
      lrow *= al;
      mrow = mnew;
    }
    float lsum = 0.f;
    short p16[4][4];
#pragma unroll
    for (int kb = 0; kb < 4; ++kb)
#pragma unroll
      for (int r = 0; r < 4; ++r) {
        float p = __expf(sv[kb][r] - mrow);
        lsum += p;
        p16[kb][r] = (short)f2bf(p);
      }
    lrow += lsum;
    // P as B-frag (slot-permuted), V^T A-frags from LDS
    s16x8 af[2];
#pragma unroll
    for (int m = 0; m < 2; ++m)
#pragma unroll
      for (int j = 0; j < 8; ++j) af[m][j] = p16[2 * m + (j >> 2)][j & 3];
    __builtin_amdgcn_s_setprio(1);
#pragma unroll
    for (int m = 0; m < 2; ++m)
#pragma unroll
      for (int d = 0; d < 4; ++d) {
        int row = d * 16 + lr;
        s16x8 vf = *reinterpret_cast<const s16x8*>(
            &Vt[cur][row * 64 + ((32 * m + 8 * lg) ^ ((row & 7) << 3))]);
        acc[d] = __builtin_amdgcn_mfma_f32_16x16x32_bf16(vf, af[m], acc[d], 0, 0, 0);
      }
    __builtin_amdgcn_s_setprio(0);
    // commit prefetched tile -> other buffer
    if (kt < qt) {
      __syncthreads();
      int nxt = cur ^ 1;
#pragma unroll
      for (int i = 0; i < 7; ++i) {
        int e = tid + i * 256;
        int k = e / 28, c = e - k * 28;
        if (c < 27)
          *reinterpret_cast<uint*>(&Ks[nxt][k * 64 + ((2 * c) ^ ((k & 7) << 3))]) = kreg[i];
        int ev = e >> 1, par = e & 1;
        int p = ev / 28, cv = ev - p * 28;
        uint u = vreg[i];
        uint uo = __shfl_xor(u, 1);
        if (cv < 27) {
          int k0 = 2 * p;
          int s0 = ((k0 >> 5) << 5) | (((k0 >> 2) & 3) << 3) | (((k0 >> 4) & 1) << 2) | (k0 & 3);
          int d = 2 * cv + par;
          uint wv2 = par ? ((uo >> 16) | (u & 0xffff0000u)) : ((u & 0xffffu) | (uo << 16));
          *reinterpret_cast<uint*>(&Vt[nxt][d * 64 + (s0 ^ ((d & 7) << 3))]) = wv2;
        }
      }
      __syncthreads();
    }
  }

  // row sum = reduce partial lrow over the 4 lanes sharing q-row lr
  lrow += __shfl_xor(lrow, 16);
  lrow += __shfl_xor(lrow, 32);
  float linv = 1.f / lrow;
  __syncthreads();
  ushort* Olds = &Ks[0][0];  // reuse: [d][q], stride 64
#pragma unroll
  for (int d = 0; d < 4; ++d)
#pragma unroll
    for (int r = 0; r < 4; ++r)
      Olds[(d * 16 + 4 * lg + r) * 64 + w * 16 + lr] = f2bf(acc[d][r] * linv);
  __syncthreads();
  for (int e = tid; e < 64 * 27; e += 256) {
    int q = e / 27, c = e - q * 27;
    uint lo = Olds[(2 * c) * 64 + q];
    uint hi = Olds[(2 * c + 1) * 64 + q];
    *reinterpret_cast<uint*>(&o[(size_t)(b * SEQ + qr0 + q) * EMBED + h * HSZ + 2 * c]) =
        lo | (hi << 16);
  }
}

// ---------------- bf16 MFMA GEMM (m97 structure: 128x128 tile, BK=64, 4 waves) ----------------
// MODE 0: C = bf16(A@B + bias)   MODE 1: C = bf16(gelu(A@B + bias))   MODE 2: C = f32(A@B+bias+resid)
template<int KSTEPS, int LDA, int LDB, int MODE>
__global__ __launch_bounds__(256) void mfma_gemm(
    const char* __restrict__ Ab, const char* __restrict__ Btb,
    const float* __restrict__ bias, const float* __restrict__ resid,
    char* __restrict__ Cb, int ncols) {
  __shared__ ushort As[8192];
  __shared__ ushort Bs[8192];
  int tid = threadIdx.x;
  int wv = tid >> 6, l = tid & 63;
  int wr = wv >> 1, wc = wv & 1;
  int lr = l & 15, lg = l >> 4;
  int tok0 = blockIdx.x << 7;
  int col0 = blockIdx.y << 7;

  const char* aptr[4]; const char* bptr[4];
#pragma unroll
  for (int is = 0; is < 4; ++is) {
    int i = is * 256 + tid;
    int row = i >> 3;
    int boff = (i & 7) << 4;
    int sw = boff ^ ((row & 7) << 4);
    aptr[is] = Ab + (size_t)(tok0 + row) * LDA + sw;
    bptr[is] = Btb + (size_t)(col0 + row) * LDB + sw;
  }

  int offA[2][4], offB[2][4];
#pragma unroll
  for (int m = 0; m < 4; ++m) {
    int rowa = wr * 64 + m * 16 + lr;
    int rowb = wc * 64 + m * 16 + lr;
    int sa = (rowa & 7) << 4, sb = (rowb & 7) << 4;
#pragma unroll
    for (int kk = 0; kk < 2; ++kk) {
      int kb = kk * 64 + lg * 16;
      offA[kk][m] = (rowa * 128 + (kb ^ sa)) >> 1;
      offB[kk][m] = (rowb * 128 + (kb ^ sb)) >> 1;
    }
  }

  f32x4 acc[4][4];
#pragma unroll
  for (int m = 0; m < 4; ++m)
#pragma unroll
    for (int n = 0; n < 4; ++n) acc[m][n] = (f32x4){0.f, 0.f, 0.f, 0.f};

  for (int ks = 0; ks < KSTEPS; ++ks) {
#pragma unroll
    for (int is = 0; is < 4; ++is) {
      gload16(aptr[is] + ks * 128, (char*)As + is * 4096 + wv * 1024);
      gload16(bptr[is] + ks * 128, (char*)Bs + is * 4096 + wv * 1024);
    }
    __syncthreads();
#pragma unroll
    for (int kk = 0; kk < 2; ++kk) {
      s16x8 af[4], bfr[4];
#pragma unroll
      for (int m = 0; m < 4; ++m) af[m] = *reinterpret_cast<const s16x8*>(&As[offA[kk][m]]);
#pragma unroll
      for (int n = 0; n < 4; ++n) bfr[n] = *reinterpret_cast<const s16x8*>(&Bs[offB[kk][n]]);
#pragma unroll
      for (int m = 0; m < 4; ++m)
#pragma unroll
        for (int n = 0; n < 4; ++n)
          acc[m][n] = __builtin_amdgcn_mfma_f32_16x16x32_bf16(af[m], bfr[n], acc[m][n], 0, 0, 0);
    }
    __syncthreads();
  }

  int tokr = tok0 + wr * 64 + lg * 4;
  int colr = col0 + wc * 64 + lr;
  float bn[4];
#pragma unroll
  for (int n = 0; n < 4; ++n) bn[n] = bias[colr + n * 16];
  if constexpr (MODE == 2) {
    float* C = (float*)Cb;
#pragma unroll
    for (int m = 0; m < 4; ++m)
#pragma unroll
      for (int r = 0; r < 4; ++r) {
        size_t rowbase = (size_t)(tokr + m * 16 + r) * ncols;
#pragma unroll
        for (int n = 0; n < 4; ++n) {
          size_t idx = rowbase + colr + n * 16;
          C[idx] = acc[m][n][r] + bn[n] + resid[idx];
        }
      }
  } else {
    ushort* C = (ushort*)Cb;
#pragma unroll
    for (int m = 0; m < 4; ++m)
#pragma unroll
      for (int r = 0; r < 4; ++r) {
        size_t rowbase = (size_t)(tokr + m * 16 + r) * ncols;
#pragma unroll
        for (int n = 0; n < 4; ++n) {
          float xg = acc[m][n][r] + bn[n];
          if constexpr (MODE == 1)
            xg = 0.5f * xg * (1.f + erff(xg * 0.70710678118654752f));
          C[rowbase + colr + n * 16] = f2bf(xg);
        }
      }
  }
}

extern "C" void kernel_launch(void* const* d_in, const int* in_sizes, int n_in,
                              void* d_out, int out_size, void* d_ws, size_t ws_size,
                              hipStream_t stream) {
  const float* x    = (const float*)d_in[0];
  const float* wq   = (const float*)d_in[1];
  const float* bq   = (const float*)d_in[2];
  const float* wk   = (const float*)d_in[3];
  const float* bk   = (const float*)d_in[4];
  const float* wv   = (const float*)d_in[5];
  const float* bv   = (const float*)d_in[6];
  const float* wo   = (const float*)d_in[7];
  const float* bo   = (const float*)d_in[8];
  const float* w1   = (const float*)d_in[9];
  const float* b1   = (const float*)d_in[10];
  const float* w2   = (const float*)d_in[11];
  const float* b2   = (const float*)d_in[12];
  const float* ln1g = (const float*)d_in[13];
  const float* ln1b = (const float*)d_in[14];
  const float* ln2g = (const float*)d_in[15];
  const float* ln2b = (const float*)d_in[16];
  float* out = (float*)d_out;

  char* wsb = (char*)d_ws;
  float*  x1    = (float*)wsb;
  ushort* ffnb  = (ushort*)(wsb + 50331648);
  ushort* hb    = (ushort*)(wsb + 50331648);
  ushort* qkvb  = (ushort*)(wsb + 75497472);
  ushort* aout  = (ushort*)(wsb + 150994944);
  ushort* h2b   = (ushort*)(wsb + 201326592);
  ushort* w1t   = (ushort*)(wsb + 226492416);
  ushort* w2t   = (ushort*)(wsb + 228261888);
  ushort* wqkvt = (ushort*)(wsb + 230031360);
  ushort* wot   = (ushort*)(wsb + 230916096);
  float*  bqkv  = (float*)(wsb + 231211008);

  // weight prep (coalesced tiled transposes)
  conv_qkvw_tiled<<<dim3(12, 2, 21), 256, 0, stream>>>(wq, wk, wv, wqkvt);
  fill_misc      <<<27, 256, 0, stream>>>(bq, bk, bv, wqkvt, bqkv);
  convT_tiled    <<<dim3(12, 12), 256, 0, stream>>>(wo, wot, EMBED, EMBED, 378, EMBED);
  convT_tiled    <<<dim3(12, 72), 256, 0, stream>>>(w1, w1t, EMBED, FFND, EMBED, FFND);
  convT_tiled    <<<dim3(72, 12), 256, 0, stream>>>(w2, w2t, FFND, EMBED, FFND, EMBED);
  pad_aout_kernel<<<(NTOK * 6 + 255) / 256, 256, 0, stream>>>(aout);

  ln_bf16_kernel<<<NTOK / 4, 256, 0, stream>>>(x, ln1g, ln1b, hb);
  mfma_gemm<EMBED / 64, EMBED * 2, EMBED * 2, 0>
      <<<dim3(NTOK / 128, QKVN / 128), 256, 0, stream>>>(
      (const char*)hb, (const char*)wqkvt, bqkv, nullptr, (char*)qkvb, QKVN);
  attn_mfma_kernel<<<BATCH * HEADS * (SEQ / 64), 256, 0, stream>>>(qkvb, aout);
  mfma_gemm<EMBED / 64, EMBED * 2, EMBED * 2, 2>
      <<<dim3(NTOK / 128, EMBED / 128), 256, 0, stream>>>(
      (const char*)aout, (const char*)wot, bo, x, (char*)x1, EMBED);
  ln_bf16_kernel<<<NTOK / 4, 256, 0, stream>>>(x1, ln2g, ln2b, h2b);
  mfma_gemm<EMBED / 64, EMBED * 2, EMBED * 2, 1>
      <<<dim3(NTOK / 128, FFND / 128), 256, 0, stream>>>(
      (const char*)h2b, (const char*)w1t, b1, nullptr, (char*)ffnb, FFND);
  mfma_gemm<FFND / 64, FFND * 2, FFND * 2, 2>
      <<<dim3(NTOK / 128, EMBED / 128), 256, 0, stream>>>(
      (const char*)ffnb, (const char*)w2t, b2, x1, (char*)out, EMBED);
}